// Round 15
// baseline (987.764 us; speedup 1.0000x reference)
//
#include <hip/hip_runtime.h>

#define NN 100000
#define NE 640000
#define HD 128
#define NG 512
#define NC 6
#define EPSV 1e-5f
#define OCT 12500   // NN/8 per dst-octant

typedef __bf16 bf16_t;
typedef bf16_t bf16x8 __attribute__((ext_vector_type(8)));
typedef float f32x4 __attribute__((ext_vector_type(4)));

__device__ __forceinline__ float b2f(unsigned int u16) {
    return __builtin_bit_cast(float, u16 << 16);
}
__device__ __forceinline__ unsigned short f2b(float f) {
    unsigned int u = __builtin_bit_cast(unsigned int, f);
    unsigned int r = (u + 0x7fffu + ((u >> 16) & 1u)) >> 16;
    return (unsigned short)r;
}

// fragment-ordered staging, half-matrix: LDS uint4 i (i<1024) holds B-frag 16B
// for (t_local=(i>>8), ks=(i>>6)&3, lane=i&63) of column-half h.
__device__ __forceinline__ int frag_src_h(int i, int h) {
    int g2 = i >> 6, ln = i & 63;
    int row = (h * 4 + (g2 >> 2)) * 16 + (ln & 15);
    return row * 16 + (g2 & 3) * 4 + (ln >> 4);
}
// full-matrix version (mfma_attn)
__device__ __forceinline__ int frag_src(int i) {
    int g2 = i >> 6, ln = i & 63;
    int row = (g2 >> 2) * 16 + (ln & 15);
    return row * 16 + (g2 & 3) * 4 + (ln >> 4);
}

// ---------------- fast zero ----------------
__global__ __launch_bounds__(256) void k_zero(uint4* __restrict__ p, int n16) {
    int i = blockIdx.x * 256 + threadIdx.x;
    if (i < n16) p[i] = (uint4){0u, 0u, 0u, 0u};
}

// ---------------- fused prep: octant count FIRST | x->bf16 cvt | weight transposes ----------------
__global__ __launch_bounds__(256) void k_prep(
    const float* __restrict__ x, unsigned short* __restrict__ xb,
    const float* __restrict__ Wa, const float* __restrict__ Wb,
    const float* __restrict__ Wc, const float* __restrict__ Wd,
    const float* __restrict__ We, unsigned short* __restrict__ Wt,
    const int* __restrict__ dst, int* __restrict__ cnt)
{
    int bid = blockIdx.x;
    if (bid < 960) {
        int oct = bid & 7;
        int widx = bid >> 3;
        int lo = oct * OCT, hi = lo + OCT;
        for (int e = widx * 256 + threadIdx.x; e < NE; e += 120 * 256) {
            int d = dst[e];
            if (d >= lo && d < hi) atomicAdd(&cnt[d], 1);
        }
    } else if (bid < 7210) {
        int i = (bid - 960) * 256 + threadIdx.x;
        float4 v0 = reinterpret_cast<const float4*>(x)[i * 2];
        float4 v1 = reinterpret_cast<const float4*>(x)[i * 2 + 1];
        unsigned short u[8] = {f2b(v0.x), f2b(v0.y), f2b(v0.z), f2b(v0.w),
                               f2b(v1.x), f2b(v1.y), f2b(v1.z), f2b(v1.w)};
        reinterpret_cast<uint4*>(xb)[i] = *reinterpret_cast<uint4*>(u);
    } else {
        int i = (bid - 7210) * 256 + threadIdx.x;
        int w = i >> 14, r = i & 16383;
        int k = r >> 7, n = r & 127;
        const float* W = (w == 0) ? Wa : (w == 1) ? Wb : (w == 2) ? Wc : (w == 3) ? Wd : We;
        Wt[w * 16384 + n * HD + k] = f2b(W[k * HD + n]);
    }
}

// ---------------- degree histogram / descending offsets / scatter perm ----------------
__global__ void k_hist(const int* __restrict__ cnt, int* __restrict__ hist, int n) {
    int i = blockIdx.x * 256 + threadIdx.x;
    if (i < n) {
        int bin = cnt[i] < 63 ? cnt[i] : 63;
        atomicAdd(&hist[bin], 1);
    }
}
__global__ void k_hscan(const int* __restrict__ hist, int* __restrict__ hoff) {
    int b = threadIdx.x;  // 64 threads; descending-exclusive: high bins first (LPT)
    int s = 0;
    for (int j = b + 1; j < 64; ++j) s += hist[j];
    hoff[b] = s;
}
__global__ void k_scatter(const int* __restrict__ cnt, int* __restrict__ hoff,
                          int* __restrict__ perm, int n) {
    int i = blockIdx.x * 256 + threadIdx.x;
    if (i < n) {
        int bin = cnt[i] < 63 ? cnt[i] : 63;
        int p = atomicAdd(&hoff[bin], 1);
        perm[p] = i;
    }
}

// ---------------- hierarchical scan ----------------
__global__ void k_scan1(const int* __restrict__ cnt, int* __restrict__ excl,
                        int* __restrict__ bsum, int n) {
    __shared__ int sh[256];
    int i = blockIdx.x * 256 + threadIdx.x;
    int v = (i < n) ? cnt[i] : 0;
    sh[threadIdx.x] = v;
    __syncthreads();
    for (int off = 1; off < 256; off <<= 1) {
        int t = (threadIdx.x >= off) ? sh[threadIdx.x - off] : 0;
        __syncthreads();
        sh[threadIdx.x] += t;
        __syncthreads();
    }
    if (i < n) excl[i] = sh[threadIdx.x] - v;
    if (threadIdx.x == 255) bsum[blockIdx.x] = sh[255];
}

__global__ void k_scan2(int* bsum, int nb) {
    __shared__ int sh[512];
    int t = threadIdx.x;
    sh[t] = (t < nb) ? bsum[t] : 0;
    __syncthreads();
    for (int off = 1; off < 512; off <<= 1) {
        int v = (t >= off) ? sh[t - off] : 0;
        __syncthreads();
        sh[t] += v;
        __syncthreads();
    }
    if (t < nb) bsum[t] = sh[t];
}

__global__ void k_scan3(const int* __restrict__ excl, const int* __restrict__ bsum,
                        int* __restrict__ row_off, int n) {
    int i = blockIdx.x * 256 + threadIdx.x;
    if (i < n) row_off[i] = excl[i] + (blockIdx.x ? bsum[blockIdx.x - 1] : 0);
    if (i == 0) row_off[n] = NE;
}

// ---------------- octant-partitioned fill ----------------
__global__ __launch_bounds__(256) void k_fill(const int* __restrict__ src,
                                              const int* __restrict__ dst,
                                              const int* __restrict__ row_off,
                                              int* __restrict__ cnt,
                                              int* __restrict__ csr) {
    int q = blockIdx.x;
    int oct = q & 7;
    int widx = q >> 3;
    int lo = oct * OCT, hi = lo + OCT;
    for (int e = widx * 256 + threadIdx.x; e < NE; e += 120 * 256) {
        int d = dst[e];
        if (d >= lo && d < hi) {
            int p = atomicSub(&cnt[d], 1);
            csr[row_off[d] + p - 1] = src[e];
        }
    }
}

// ---------------- FUSED SAGE layer (degree-sorted rows via perm) ----------------
// 8 waves x 16 rows = 128 rows/block, 512 threads, 32 KB LDS (half-column tiles).
// Rows processed in descending-degree order -> uniform wave runtimes, no tail.
__global__ __launch_bounds__(512) void k_sage(
    const unsigned short* __restrict__ X,
    const int* __restrict__ row_off, const int* __restrict__ csr,
    const int* __restrict__ perm,
    const unsigned short* __restrict__ Wlt, const unsigned short* __restrict__ Wrt,
    const float* __restrict__ bias, unsigned short* __restrict__ out, int M)
{
    __shared__ uint4 wlds[2048];  // 32 KB: [0,1024)=Wl half, [1024,2048)=Wr half
    const int wid = threadIdx.x >> 6;
    const int lane = threadIdx.x & 63;
    const int lrow = lane & 15;
    const int lkg = lane >> 4;
    const int r0 = blockIdx.x * 128 + wid * 16;

    const uint4* gl = reinterpret_cast<const uint4*>(Wlt);
    const uint4* gr = reinterpret_cast<const uint4*>(Wrt);
    // stage half 0 (loads land while the gather runs)
    for (int i = threadIdx.x; i < 1024; i += 512) {
        wlds[i] = gl[frag_src_h(i, 0)];
        wlds[1024 + i] = gr[frag_src_h(i, 0)];
    }

    int idx = r0 + lrow;
    idx = idx < M ? idx : M - 1;
    int row = perm[idx];
    int beg = row_off[row], end = row_off[row + 1];

    // output row mapping for this lane (r = 0..3)
    int pr[4];
    bool pv[4];
#pragma unroll
    for (int r = 0; r < 4; ++r) {
        int oi = r0 + lkg * 4 + r;
        pv[r] = oi < M;
        pr[r] = perm[pv[r] ? oi : M - 1];
    }

    float accg[4][8];
#pragma unroll
    for (int ks = 0; ks < 4; ++ks)
#pragma unroll
        for (int j = 0; j < 8; ++j) accg[ks][j] = 0.f;

    const unsigned short* Xk = X + lkg * 8;
    for (int j = beg; j < end; j += 2) {
        int s0 = csr[j];
        const unsigned short* p0 = Xk + (size_t)s0 * HD;
        uint4 w0 = *reinterpret_cast<const uint4*>(p0);
        uint4 w1 = *reinterpret_cast<const uint4*>(p0 + 32);
        uint4 w2 = *reinterpret_cast<const uint4*>(p0 + 64);
        uint4 w3 = *reinterpret_cast<const uint4*>(p0 + 96);
        bool ok1 = (j + 1) < end;
        int s1 = csr[ok1 ? j + 1 : j];
        const unsigned short* p1 = Xk + (size_t)s1 * HD;
        uint4 y0, y1, y2, y3;
        if (ok1) {
            y0 = *reinterpret_cast<const uint4*>(p1);
            y1 = *reinterpret_cast<const uint4*>(p1 + 32);
            y2 = *reinterpret_cast<const uint4*>(p1 + 64);
            y3 = *reinterpret_cast<const uint4*>(p1 + 96);
        }
        accg[0][0] += b2f(w0.x & 0xffffu); accg[0][1] += b2f(w0.x >> 16);
        accg[0][2] += b2f(w0.y & 0xffffu); accg[0][3] += b2f(w0.y >> 16);
        accg[0][4] += b2f(w0.z & 0xffffu); accg[0][5] += b2f(w0.z >> 16);
        accg[0][6] += b2f(w0.w & 0xffffu); accg[0][7] += b2f(w0.w >> 16);
        accg[1][0] += b2f(w1.x & 0xffffu); accg[1][1] += b2f(w1.x >> 16);
        accg[1][2] += b2f(w1.y & 0xffffu); accg[1][3] += b2f(w1.y >> 16);
        accg[1][4] += b2f(w1.z & 0xffffu); accg[1][5] += b2f(w1.z >> 16);
        accg[1][6] += b2f(w1.w & 0xffffu); accg[1][7] += b2f(w1.w >> 16);
        accg[2][0] += b2f(w2.x & 0xffffu); accg[2][1] += b2f(w2.x >> 16);
        accg[2][2] += b2f(w2.y & 0xffffu); accg[2][3] += b2f(w2.y >> 16);
        accg[2][4] += b2f(w2.z & 0xffffu); accg[2][5] += b2f(w2.z >> 16);
        accg[2][6] += b2f(w2.w & 0xffffu); accg[2][7] += b2f(w2.w >> 16);
        accg[3][0] += b2f(w3.x & 0xffffu); accg[3][1] += b2f(w3.x >> 16);
        accg[3][2] += b2f(w3.y & 0xffffu); accg[3][3] += b2f(w3.y >> 16);
        accg[3][4] += b2f(w3.z & 0xffffu); accg[3][5] += b2f(w3.z >> 16);
        accg[3][6] += b2f(w3.w & 0xffffu); accg[3][7] += b2f(w3.w >> 16);
        if (ok1) {
            accg[0][0] += b2f(y0.x & 0xffffu); accg[0][1] += b2f(y0.x >> 16);
            accg[0][2] += b2f(y0.y & 0xffffu); accg[0][3] += b2f(y0.y >> 16);
            accg[0][4] += b2f(y0.z & 0xffffu); accg[0][5] += b2f(y0.z >> 16);
            accg[0][6] += b2f(y0.w & 0xffffu); accg[0][7] += b2f(y0.w >> 16);
            accg[1][0] += b2f(y1.x & 0xffffu); accg[1][1] += b2f(y1.x >> 16);
            accg[1][2] += b2f(y1.y & 0xffffu); accg[1][3] += b2f(y1.y >> 16);
            accg[1][4] += b2f(y1.z & 0xffffu); accg[1][5] += b2f(y1.z >> 16);
            accg[1][6] += b2f(y1.w & 0xffffu); accg[1][7] += b2f(y1.w >> 16);
            accg[2][0] += b2f(y2.x & 0xffffu); accg[2][1] += b2f(y2.x >> 16);
            accg[2][2] += b2f(y2.y & 0xffffu); accg[2][3] += b2f(y2.y >> 16);
            accg[2][4] += b2f(y2.z & 0xffffu); accg[2][5] += b2f(y2.z >> 16);
            accg[2][6] += b2f(y2.w & 0xffffu); accg[2][7] += b2f(y2.w >> 16);
            accg[3][0] += b2f(y3.x & 0xffffu); accg[3][1] += b2f(y3.x >> 16);
            accg[3][2] += b2f(y3.y & 0xffffu); accg[3][3] += b2f(y3.y >> 16);
            accg[3][4] += b2f(y3.z & 0xffffu); accg[3][5] += b2f(y3.z >> 16);
            accg[3][6] += b2f(y3.w & 0xffffu); accg[3][7] += b2f(y3.w >> 16);
        }
    }

    float inv = 1.f / fmaxf((float)(end - beg), 1.f);
    bf16x8 a1[4], a2f[4];
#pragma unroll
    for (int ks = 0; ks < 4; ++ks) {
        unsigned short u[8];
#pragma unroll
        for (int j = 0; j < 8; ++j) u[j] = f2b(accg[ks][j] * inv);
        a1[ks] = *reinterpret_cast<bf16x8*>(u);
    }
    const unsigned short* p2 = X + (size_t)row * HD + lkg * 8;
#pragma unroll
    for (int ks = 0; ks < 4; ++ks)
        a2f[ks] = *reinterpret_cast<const bf16x8*>(p2 + ks * 32);

    // -------- half 0: cols 0..63 --------
    {
        f32x4 acc[4];
#pragma unroll
        for (int t = 0; t < 4; ++t) {
            float b = bias[t * 16 + lrow];
            acc[t] = (f32x4){b, b, b, b};
        }
        __syncthreads();
#pragma unroll
        for (int ks = 0; ks < 4; ++ks) {
#pragma unroll
            for (int t = 0; t < 4; ++t) {
                int fi = (t * 4 + ks) * 64 + lane;
                bf16x8 bl = __builtin_bit_cast(bf16x8, wlds[fi]);
                bf16x8 br = __builtin_bit_cast(bf16x8, wlds[1024 + fi]);
                acc[t] = __builtin_amdgcn_mfma_f32_16x16x32_bf16(a1[ks], bl, acc[t], 0, 0, 0);
                acc[t] = __builtin_amdgcn_mfma_f32_16x16x32_bf16(a2f[ks], br, acc[t], 0, 0, 0);
            }
        }
#pragma unroll
        for (int t = 0; t < 4; ++t)
#pragma unroll
            for (int r = 0; r < 4; ++r)
                if (pv[r])
                    out[(size_t)pr[r] * HD + t * 16 + lrow] = f2b(fmaxf(acc[t][r], 0.f));
    }

    // -------- half 1: cols 64..127 --------
    __syncthreads();
    for (int i = threadIdx.x; i < 1024; i += 512) {
        wlds[i] = gl[frag_src_h(i, 1)];
        wlds[1024 + i] = gr[frag_src_h(i, 1)];
    }
    {
        f32x4 acc[4];
#pragma unroll
        for (int t = 0; t < 4; ++t) {
            float b = bias[(4 + t) * 16 + lrow];
            acc[t] = (f32x4){b, b, b, b};
        }
        __syncthreads();
#pragma unroll
        for (int ks = 0; ks < 4; ++ks) {
#pragma unroll
            for (int t = 0; t < 4; ++t) {
                int fi = (t * 4 + ks) * 64 + lane;
                bf16x8 bl = __builtin_bit_cast(bf16x8, wlds[fi]);
                bf16x8 br = __builtin_bit_cast(bf16x8, wlds[1024 + fi]);
                acc[t] = __builtin_amdgcn_mfma_f32_16x16x32_bf16(a1[ks], bl, acc[t], 0, 0, 0);
                acc[t] = __builtin_amdgcn_mfma_f32_16x16x32_bf16(a2f[ks], br, acc[t], 0, 0, 0);
            }
        }
#pragma unroll
        for (int t = 0; t < 4; ++t)
#pragma unroll
            for (int r = 0; r < 4; ++r)
                if (pv[r])
                    out[(size_t)pr[r] * HD + (4 + t) * 16 + lrow] = f2b(fmaxf(acc[t][r], 0.f));
    }
}

// ---------------- fused attention, frag-ordered LDS ----------------
__global__ __launch_bounds__(256) void mfma_attn(
    const unsigned short* __restrict__ A1, const unsigned short* __restrict__ W1t,
    const float* __restrict__ bias, const float* __restrict__ Wc2,
    const float* __restrict__ bc2, float* __restrict__ a2, int M)
{
    __shared__ uint4 wlds[2048];
    const int wid = threadIdx.x >> 6;
    const int lane = threadIdx.x & 63;
    const int lrow = lane & 15;
    const int lkg = lane >> 4;
    const int r0 = blockIdx.x * 128 + wid * 32;

    const uint4* g4 = reinterpret_cast<const uint4*>(W1t);
    for (int i = threadIdx.x; i < 2048; i += 256)
        wlds[i] = g4[frag_src(i)];

    bf16x8 a[2][4];
#pragma unroll
    for (int g = 0; g < 2; ++g) {
        int row = r0 + g * 16 + lrow;
        row = row < M ? row : M - 1;
        const unsigned short* p = A1 + (size_t)row * HD + lkg * 8;
#pragma unroll
        for (int ks = 0; ks < 4; ++ks)
            a[g][ks] = *reinterpret_cast<const bf16x8*>(p + ks * 32);
    }

    f32x4 acc[2][8];
#pragma unroll
    for (int t = 0; t < 8; ++t) {
        float b = bias[t * 16 + lrow];
        acc[0][t] = (f32x4){b, b, b, b};
        acc[1][t] = (f32x4){b, b, b, b};
    }

    __syncthreads();

#pragma unroll
    for (int ks = 0; ks < 4; ++ks) {
#pragma unroll
        for (int t = 0; t < 8; ++t) {
            bf16x8 b = __builtin_bit_cast(bf16x8, wlds[(t * 4 + ks) * 64 + lane]);
            acc[0][t] = __builtin_amdgcn_mfma_f32_16x16x32_bf16(a[0][ks], b, acc[0][t], 0, 0, 0);
            acc[1][t] = __builtin_amdgcn_mfma_f32_16x16x32_bf16(a[1][ks], b, acc[1][t], 0, 0, 0);
        }
    }

    float p0[2][4] = {{0.f, 0.f, 0.f, 0.f}, {0.f, 0.f, 0.f, 0.f}};
    float p1[2][4] = {{0.f, 0.f, 0.f, 0.f}, {0.f, 0.f, 0.f, 0.f}};
#pragma unroll
    for (int t = 0; t < 8; ++t) {
        float2 wv = reinterpret_cast<const float2*>(Wc2)[t * 16 + lrow];
#pragma unroll
        for (int g = 0; g < 2; ++g)
#pragma unroll
            for (int r = 0; r < 4; ++r) {
                float tv = tanhf(acc[g][t][r]);
                p0[g][r] = fmaf(tv, wv.x, p0[g][r]);
                p1[g][r] = fmaf(tv, wv.y, p1[g][r]);
            }
    }
#pragma unroll
    for (int off = 1; off < 16; off <<= 1) {
#pragma unroll
        for (int g = 0; g < 2; ++g)
#pragma unroll
            for (int r = 0; r < 4; ++r) {
                p0[g][r] += __shfl_xor(p0[g][r], off, 64);
                p1[g][r] += __shfl_xor(p1[g][r], off, 64);
            }
    }
    if (lrow == 0) {
        float B0 = bc2[0], B1 = bc2[1];
#pragma unroll
        for (int g = 0; g < 2; ++g)
#pragma unroll
            for (int r = 0; r < 4; ++r) {
                int row = r0 + g * 16 + lkg * 4 + r;
                if (row < M) {
                    float u0 = p0[g][r] + B0, u1 = p1[g][r] + B1;
                    float m = fmaxf(u0, u1);
                    float e0 = expf(u0 - m), e1 = expf(u1 - m);
                    float inv = 1.f / (e0 + e1);
                    reinterpret_cast<float2*>(a2)[row] = (float2){e0 * inv, e1 * inv};
                }
            }
    }
}

// ---------------- pos+colsum (blocks [0,NG)) and adj (blocks [NG,NG+120)) merged ----------------
__global__ __launch_bounds__(1024) void k_posadj(const unsigned short* __restrict__ h,
                                                 const float* __restrict__ a2,
                                                 const int* __restrict__ batch,
                                                 const int* __restrict__ src,
                                                 const int* __restrict__ dst,
                                                 float* __restrict__ pos_out,
                                                 float* __restrict__ csum,
                                                 float* __restrict__ adj) {
    __shared__ float4 sh[16][64];
    __shared__ float shadj[NG * 4];
    int bid = blockIdx.x;
    if (bid < NG) {
        int g = bid;
        int lo = 0, hi = NN;
        while (lo < hi) { int m = (lo + hi) >> 1; if (batch[m] < g) lo = m + 1; else hi = m; }
        int beg = lo;
        hi = NN;
        while (lo < hi) { int m = (lo + hi) >> 1; if (batch[m] < g + 1) lo = m + 1; else hi = m; }
        int end = lo;
        int grp = threadIdx.x >> 6;
        int lane = threadIdx.x & 63;
        float4 acc = {0.f, 0.f, 0.f, 0.f};
        for (int i = beg + grp * 2; i < end; i += 32) {
            int i1 = i + 1;
            bool ok1 = i1 < end;
            float a0 = a2[i * 2];
            unsigned int v0 = *reinterpret_cast<const unsigned int*>(h + (size_t)i * HD + lane * 2);
            float a1 = ok1 ? a2[i1 * 2] : 0.f;
            unsigned int v1 = ok1 ? *reinterpret_cast<const unsigned int*>(h + (size_t)i1 * HD + lane * 2) : 0u;
            float f0 = b2f(v0 & 0xffffu), f1 = b2f(v0 >> 16);
            float g0 = b2f(v1 & 0xffffu), g1 = b2f(v1 >> 16);
            acc.x = fmaf(a0, f0, fmaf(a1, g0, acc.x));
            acc.y = fmaf(a0, f1, fmaf(a1, g1, acc.y));
            acc.z += f0 + g0;
            acc.w += f1 + g1;
        }
        sh[grp][lane] = acc;
        __syncthreads();
        if (threadIdx.x < 64) {
            float4 s = sh[0][lane];
#pragma unroll
            for (int k = 1; k < 16; ++k) {
                float4 t = sh[k][lane];
                s.x += t.x; s.y += t.y; s.z += t.z; s.w += t.w;
            }
            reinterpret_cast<float2*>(pos_out)[g * 64 + lane] = (float2){s.x, s.y};
            atomicAdd(&csum[lane * 2], s.z);
            atomicAdd(&csum[lane * 2 + 1], s.w);
        }
    } else {
        for (int i = threadIdx.x; i < NG * 4; i += 1024) shadj[i] = 0.f;
        __syncthreads();
        for (int e = (bid - NG) * 1024 + threadIdx.x; e < NE; e += 120 * 1024) {
            int s = src[e], d = dst[e];
            int bs = batch[s], bd = batch[d];
            if (bs != bd) continue;
            float a0s = a2[2 * s], a1s = a2[2 * s + 1];
            float a0d = a2[2 * d], a1d = a2[2 * d + 1];
            float* A = shadj + bs * 4;
            atomicAdd(A + 0, a0s * a0d);
            atomicAdd(A + 1, a0s * a1d);
            atomicAdd(A + 2, a1s * a0d);
            atomicAdd(A + 3, a1s * a1d);
        }
        __syncthreads();
        for (int i = threadIdx.x; i < NG * 4; i += 1024) {
            float v = shadj[i];
            if (v != 0.f) atomicAdd(&adj[i], v);
        }
    }
}

// ---------------- tail: gemb + penalty ----------------
__global__ __launch_bounds__(512) void k_tail(const float* __restrict__ csum,
                                              float* __restrict__ gemb_out,
                                              const float* __restrict__ adj,
                                              float* __restrict__ pen) {
    int bid = blockIdx.x;
    if (bid < 128) {
        int i = bid * 512 + threadIdx.x;
        gemb_out[i] = csum[i & 127] * (1.f / (float)NN);
    } else {
        __shared__ float sh[512];
        int g = threadIdx.x;
        float x0 = adj[g * 4], x1 = adj[g * 4 + 1], x2 = adj[g * 4 + 2], x3 = adj[g * 4 + 3];
        float l0 = fabsf(x0) + fabsf(x1);
        float l1 = fabsf(x2) + fabsf(x3);
        float d0 = x0 / fmaxf(l0, EPSV);
        float d1 = x3 / fmaxf(l1, EPSV);
        sh[g] = 0.5f * ((d0 - 1.f) * (d0 - 1.f) + (d1 - 1.f) * (d1 - 1.f));
        __syncthreads();
        for (int off = 256; off >= 1; off >>= 1) {
            if (g < off) sh[g] += sh[g + off];
            __syncthreads();
        }
        if (g == 0) pen[0] = sh[0] * (1.f / (float)NG);
    }
}

// ---------------- fp32 head GEMM (512 rows): out = relu(A@W + b) ----------------
__global__ __launch_bounds__(256) void gemm_head(
    const float* __restrict__ A, const float* __restrict__ W,
    const float* __restrict__ bias, float* __restrict__ out, int M)
{
    const int tid = threadIdx.x;
    const int w = __builtin_amdgcn_readfirstlane(tid >> 6);
    const int lane = tid & 63;
    const int r0 = blockIdx.x * 32 + w * 8;
    if (r0 >= M) return;
    const int c0 = lane, c1 = lane + 64;
    float acc0[8], acc1[8];
    const float b0 = bias[c0], b1 = bias[c1];
#pragma unroll
    for (int r = 0; r < 8; ++r) { acc0[r] = b0; acc1[r] = b1; }
    const float* Ap = A + (size_t)r0 * HD;
    for (int k4 = 0; k4 < HD / 4; ++k4) {
        float4 a[8];
#pragma unroll
        for (int r = 0; r < 8; ++r)
            a[r] = *reinterpret_cast<const float4*>(Ap + r * HD + k4 * 4);
#pragma unroll
        for (int j = 0; j < 4; ++j) {
            const int k = k4 * 4 + j;
            const float w0 = W[k * HD + c0];
            const float w1 = W[k * HD + c1];
#pragma unroll
            for (int r = 0; r < 8; ++r) {
                const float av = (j == 0) ? a[r].x : (j == 1) ? a[r].y
                               : (j == 2) ? a[r].z : a[r].w;
                acc0[r] = fmaf(av, w0, acc0[r]);
                acc1[r] = fmaf(av, w1, acc1[r]);
            }
        }
    }
#pragma unroll
    for (int r = 0; r < 8; ++r) {
        out[(size_t)(r0 + r) * HD + c0] = fmaxf(acc0[r], 0.f);
        out[(size_t)(r0 + r) * HD + c1] = fmaxf(acc1[r], 0.f);
    }
}

// ---------------- final head: logits + log_softmax ----------------
__global__ void k_head(const float* __restrict__ z, const float* __restrict__ Wl2,
                       const float* __restrict__ bl2, float* __restrict__ out0) {
    int g = blockIdx.x * blockDim.x + threadIdx.x;
    if (g >= NG) return;
    float l[NC];
#pragma unroll
    for (int c = 0; c < NC; ++c) l[c] = bl2[c];
    for (int k = 0; k < HD; ++k) {
        float zv = z[(size_t)g * HD + k];
#pragma unroll
        for (int c = 0; c < NC; ++c) l[c] = fmaf(zv, Wl2[k * NC + c], l[c]);
    }
    float m = l[0];
#pragma unroll
    for (int c = 1; c < NC; ++c) m = fmaxf(m, l[c]);
    float sum = 0.f;
#pragma unroll
    for (int c = 0; c < NC; ++c) sum += expf(l[c] - m);
    float lse = m + logf(sum);
#pragma unroll
    for (int c = 0; c < NC; ++c) out0[g * NC + c] = l[c] - lse;
}

extern "C" void kernel_launch(void* const* d_in, const int* in_sizes, int n_in,
                              void* d_out, int out_size, void* d_ws, size_t ws_size,
                              hipStream_t stream) {
    const float* x   = (const float*)d_in[0];
    const int*   ei  = (const int*)d_in[1];
    const int*   src = ei;
    const int*   dst = ei + NE;
    const int*   batch = (const int*)d_in[2];
    const float* W1l = (const float*)d_in[4];
    const float* b1l = (const float*)d_in[5];
    const float* W1r = (const float*)d_in[6];
    const float* W2l = (const float*)d_in[7];
    const float* b2l = (const float*)d_in[8];
    const float* W2r = (const float*)d_in[9];
    const float* Wc1 = (const float*)d_in[10];
    const float* bc1 = (const float*)d_in[11];
    const float* Wc2 = (const float*)d_in[12];
    const float* bc2 = (const float*)d_in[13];
    const float* Wl1 = (const float*)d_in[14];
    const float* bl1 = (const float*)d_in[15];
    const float* Wl2 = (const float*)d_in[16];
    const float* bl2 = (const float*)d_in[17];

    char* ws = (char*)d_ws;
    const size_t BB = (size_t)NN * HD * 2;  // 25,600,000
    unsigned short* xb   = (unsigned short*)(ws);
    unsigned short* bufB = (unsigned short*)(ws + BB);
    size_t O = 2 * BB;  // 51,200,000
    // zeroed region (single k_zero): cnt | adj | csum | hist | hoff  (409216 B)
    int*   cnt     = (int*)(ws + O);                 // 400000 B
    float* adj     = (float*)(ws + O + 400000);      // 8192 B
    float* csum    = (float*)(ws + O + 408192);      // 512 B
    int*   hist    = (int*)(ws + O + 408704);        // 256 B
    int*   hoff    = (int*)(ws + O + 408960);        // 256 B
    // non-zeroed scratch
    int*   row_off = (int*)(ws + O + 409216);        // 400064 B
    int*   excl    = (int*)(ws + O + 809280);        // 400000 B
    int*   bsum    = (int*)(ws + O + 1209280);       // 4096 B
    int*   csr     = (int*)(ws + O + 1213376);       // 2560000 B
    float* a2      = (float*)(ws + O + 3773376);     // 800000 B
    float* zbuf    = (float*)(ws + O + 4573376);     // 262144 B
    int*   perm    = (int*)(ws + O + 4835520);       // 400000 B
    unsigned short* w1lt = (unsigned short*)(ws + O + 5235520);  // 5*32768 B
    unsigned short* w1rt = w1lt + 16384;
    unsigned short* w2lt = w1rt + 16384;
    unsigned short* w2rt = w2lt + 16384;
    unsigned short* wc1t = w2rt + 16384;

    float* out0 = (float*)d_out;     // 512*6
    float* pos  = out0 + NG * NC;    // 512*128
    float* gemb = pos + NG * HD;     // 512*128
    float* pen  = gemb + NG * HD;    // 1

    // fast zero of cnt+adj+csum+hist+hoff: 25576 uint4s
    k_zero<<<100, 256, 0, stream>>>((uint4*)(ws + O), 25576);
    // fused prep: count (first, overlaps) | cvt | weight transposes
    k_prep<<<7530, 256, 0, stream>>>(x, xb, W1l, W1r, W2l, W2r, Wc1, w1lt, dst, cnt);
    // degree-sorted permutation (LPT): hist -> descending offsets -> scatter
    k_hist<<<391, 256, 0, stream>>>(cnt, hist, NN);
    k_hscan<<<1, 64, 0, stream>>>(hist, hoff);
    k_scatter<<<391, 256, 0, stream>>>(cnt, hoff, perm, NN);
    // hierarchical scan: cnt -> row_off
    k_scan1<<<391, 256, 0, stream>>>(cnt, excl, bsum, NN);
    k_scan2<<<1, 512, 0, stream>>>(bsum, 391);
    k_scan3<<<391, 256, 0, stream>>>(excl, bsum, row_off, NN);
    // octant fill (consumes cnt via count-down)
    k_fill<<<960, 256, 0, stream>>>(src, dst, row_off, cnt, csr);

    const int SAGE_GRID = (NN + 127) / 128;  // 782 (128 rows/block, 512 threads, 32 KB LDS)
    // Layer 1: h1 = relu(gather_mean(xb)@W1l + xb@W1r + b1l) -> bufB
    k_sage<<<SAGE_GRID, 512, 0, stream>>>(xb, row_off, csr, perm, w1lt, w1rt, b1l, bufB, NN);
    // Layer 2: h2 = relu(gather_mean(bufB)@W2l + bufB@W2r + b2l) -> xb
    k_sage<<<SAGE_GRID, 512, 0, stream>>>(bufB, row_off, csr, perm, w2lt, w2rt, b2l, xb, NN);
    // fused attention: a = softmax(tanh(h2@Wc1+bc1)@Wc2 + bc2)
    mfma_attn<<<(NN + 127) / 128, 256, 0, stream>>>(xb, wc1t, bc1, Wc2, bc2, a2, NN);
    // pos+colsum (512 blocks) and adj (120 blocks) in one dispatch
    k_posadj<<<NG + 120, 1024, 0, stream>>>(xb, a2, batch, src, dst, pos, csum, adj);
    // gemb + penalty
    k_tail<<<129, 512, 0, stream>>>(csum, gemb, adj, pen);
    // head
    gemm_head<<<NG / 32, 256, 0, stream>>>(pos, Wl1, bl1, zbuf, NG);
    k_head<<<2, 256, 0, stream>>>(zbuf, Wl2, bl2, out0);
}

// Round 16
// 277.413 us; speedup vs baseline: 3.5606x; 3.5606x over previous
//
#include <hip/hip_runtime.h>

#define NN 100000
#define NE 640000
#define HD 128
#define NG 512
#define NC 6
#define EPSV 1e-5f
#define OCT 12500   // NN/8 per dst-octant
#define NHB 391     // histogram blocks (ceil(NN/256))

typedef __bf16 bf16_t;
typedef bf16_t bf16x8 __attribute__((ext_vector_type(8)));
typedef float f32x4 __attribute__((ext_vector_type(4)));

__device__ __forceinline__ float b2f(unsigned int u16) {
    return __builtin_bit_cast(float, u16 << 16);
}
__device__ __forceinline__ unsigned short f2b(float f) {
    unsigned int u = __builtin_bit_cast(unsigned int, f);
    unsigned int r = (u + 0x7fffu + ((u >> 16) & 1u)) >> 16;
    return (unsigned short)r;
}

__device__ __forceinline__ int frag_src_h(int i, int h) {
    int g2 = i >> 6, ln = i & 63;
    int row = (h * 4 + (g2 >> 2)) * 16 + (ln & 15);
    return row * 16 + (g2 & 3) * 4 + (ln >> 4);
}
__device__ __forceinline__ int frag_src(int i) {
    int g2 = i >> 6, ln = i & 63;
    int row = (g2 >> 2) * 16 + (ln & 15);
    return row * 16 + (g2 & 3) * 4 + (ln >> 4);
}

// ---------------- fast zero ----------------
__global__ __launch_bounds__(256) void k_zero(uint4* __restrict__ p, int n16) {
    int i = blockIdx.x * 256 + threadIdx.x;
    if (i < n16) p[i] = (uint4){0u, 0u, 0u, 0u};
}

// ---------------- fused prep: octant count FIRST | x->bf16 cvt | weight transposes ----------------
__global__ __launch_bounds__(256) void k_prep(
    const float* __restrict__ x, unsigned short* __restrict__ xb,
    const float* __restrict__ Wa, const float* __restrict__ Wb,
    const float* __restrict__ Wc, const float* __restrict__ Wd,
    const float* __restrict__ We, unsigned short* __restrict__ Wt,
    const int* __restrict__ dst, int* __restrict__ cnt)
{
    int bid = blockIdx.x;
    if (bid < 960) {
        int oct = bid & 7;
        int widx = bid >> 3;
        int lo = oct * OCT, hi = lo + OCT;
        for (int e = widx * 256 + threadIdx.x; e < NE; e += 120 * 256) {
            int d = dst[e];
            if (d >= lo && d < hi) atomicAdd(&cnt[d], 1);
        }
    } else if (bid < 7210) {
        int i = (bid - 960) * 256 + threadIdx.x;
        float4 v0 = reinterpret_cast<const float4*>(x)[i * 2];
        float4 v1 = reinterpret_cast<const float4*>(x)[i * 2 + 1];
        unsigned short u[8] = {f2b(v0.x), f2b(v0.y), f2b(v0.z), f2b(v0.w),
                               f2b(v1.x), f2b(v1.y), f2b(v1.z), f2b(v1.w)};
        reinterpret_cast<uint4*>(xb)[i] = *reinterpret_cast<uint4*>(u);
    } else {
        int i = (bid - 7210) * 256 + threadIdx.x;
        int w = i >> 14, r = i & 16383;
        int k = r >> 7, n = r & 127;
        const float* W = (w == 0) ? Wa : (w == 1) ? Wb : (w == 2) ? Wc : (w == 3) ? Wd : We;
        Wt[w * 16384 + n * HD + k] = f2b(W[k * HD + n]);
    }
}

// ---------------- contention-free counting sort (LPT permutation) ----------------
// 1) per-block 64-bin LDS histogram -> P[block][bin] (plain stores)
__global__ __launch_bounds__(256) void k_hist2(const int* __restrict__ cnt,
                                               int* __restrict__ P, int n) {
    __shared__ int h[64];
    if (threadIdx.x < 64) h[threadIdx.x] = 0;
    __syncthreads();
    int i = blockIdx.x * 256 + threadIdx.x;
    if (i < n) {
        int bin = cnt[i] < 63 ? cnt[i] : 63;
        atomicAdd(&h[bin], 1);
    }
    __syncthreads();
    if (threadIdx.x < 64) P[blockIdx.x * 64 + threadIdx.x] = h[threadIdx.x];
}

// 2) per-bin column scan: P[b][bin] <- sum_{b'<b} P[b'][bin]; totals[bin] = column sum
__global__ __launch_bounds__(512) void k_coltot(int* __restrict__ P,
                                                int* __restrict__ totals) {
    __shared__ int sh[512];
    int bin = blockIdx.x;
    int t = threadIdx.x;
    int v = (t < NHB) ? P[t * 64 + bin] : 0;
    sh[t] = v;
    __syncthreads();
    for (int off = 1; off < 512; off <<= 1) {
        int u = (t >= off) ? sh[t - off] : 0;
        __syncthreads();
        sh[t] += u;
        __syncthreads();
    }
    if (t < NHB) P[t * 64 + bin] = sh[t] - v;  // exclusive
    if (t == NHB - 1) totals[bin] = sh[t];
}

// 3) descending-bin offsets (high-degree bins first = LPT launch order)
__global__ void k_binoff(const int* __restrict__ totals, int* __restrict__ boff) {
    int b = threadIdx.x;  // 64
    int s = 0;
    for (int j = b + 1; j < 64; ++j) s += totals[j];
    boff[b] = s;
}

// 4) scatter: slot = boff[bin] + colbase[block][bin] + LDS-local rank
__global__ __launch_bounds__(256) void k_scatter2(const int* __restrict__ cnt,
                                                  const int* __restrict__ P,
                                                  const int* __restrict__ boff,
                                                  int* __restrict__ perm, int n) {
    __shared__ int lcnt[64];
    if (threadIdx.x < 64) lcnt[threadIdx.x] = 0;
    __syncthreads();
    int i = blockIdx.x * 256 + threadIdx.x;
    if (i < n) {
        int bin = cnt[i] < 63 ? cnt[i] : 63;
        int rank = atomicAdd(&lcnt[bin], 1);
        perm[boff[bin] + P[blockIdx.x * 64 + bin] + rank] = i;
    }
}

// ---------------- hierarchical scan ----------------
__global__ void k_scan1(const int* __restrict__ cnt, int* __restrict__ excl,
                        int* __restrict__ bsum, int n) {
    __shared__ int sh[256];
    int i = blockIdx.x * 256 + threadIdx.x;
    int v = (i < n) ? cnt[i] : 0;
    sh[threadIdx.x] = v;
    __syncthreads();
    for (int off = 1; off < 256; off <<= 1) {
        int t = (threadIdx.x >= off) ? sh[threadIdx.x - off] : 0;
        __syncthreads();
        sh[threadIdx.x] += t;
        __syncthreads();
    }
    if (i < n) excl[i] = sh[threadIdx.x] - v;
    if (threadIdx.x == 255) bsum[blockIdx.x] = sh[255];
}

__global__ void k_scan2(int* bsum, int nb) {
    __shared__ int sh[512];
    int t = threadIdx.x;
    sh[t] = (t < nb) ? bsum[t] : 0;
    __syncthreads();
    for (int off = 1; off < 512; off <<= 1) {
        int v = (t >= off) ? sh[t - off] : 0;
        __syncthreads();
        sh[t] += v;
        __syncthreads();
    }
    if (t < nb) bsum[t] = sh[t];
}

__global__ void k_scan3(const int* __restrict__ excl, const int* __restrict__ bsum,
                        int* __restrict__ row_off, int n) {
    int i = blockIdx.x * 256 + threadIdx.x;
    if (i < n) row_off[i] = excl[i] + (blockIdx.x ? bsum[blockIdx.x - 1] : 0);
    if (i == 0) row_off[n] = NE;
}

// ---------------- octant-partitioned fill ----------------
__global__ __launch_bounds__(256) void k_fill(const int* __restrict__ src,
                                              const int* __restrict__ dst,
                                              const int* __restrict__ row_off,
                                              int* __restrict__ cnt,
                                              int* __restrict__ csr) {
    int q = blockIdx.x;
    int oct = q & 7;
    int widx = q >> 3;
    int lo = oct * OCT, hi = lo + OCT;
    for (int e = widx * 256 + threadIdx.x; e < NE; e += 120 * 256) {
        int d = dst[e];
        if (d >= lo && d < hi) {
            int p = atomicSub(&cnt[d], 1);
            csr[row_off[d] + p - 1] = src[e];
        }
    }
}

// ---------------- FUSED SAGE layer (degree-sorted rows via perm) ----------------
__global__ __launch_bounds__(512) void k_sage(
    const unsigned short* __restrict__ X,
    const int* __restrict__ row_off, const int* __restrict__ csr,
    const int* __restrict__ perm,
    const unsigned short* __restrict__ Wlt, const unsigned short* __restrict__ Wrt,
    const float* __restrict__ bias, unsigned short* __restrict__ out, int M)
{
    __shared__ uint4 wlds[2048];  // 32 KB
    const int wid = threadIdx.x >> 6;
    const int lane = threadIdx.x & 63;
    const int lrow = lane & 15;
    const int lkg = lane >> 4;
    const int r0 = blockIdx.x * 128 + wid * 16;

    const uint4* gl = reinterpret_cast<const uint4*>(Wlt);
    const uint4* gr = reinterpret_cast<const uint4*>(Wrt);
    for (int i = threadIdx.x; i < 1024; i += 512) {
        wlds[i] = gl[frag_src_h(i, 0)];
        wlds[1024 + i] = gr[frag_src_h(i, 0)];
    }

    int idx = r0 + lrow;
    idx = idx < M ? idx : M - 1;
    int row = perm[idx];
    int beg = row_off[row], end = row_off[row + 1];

    int pr[4];
    bool pv[4];
#pragma unroll
    for (int r = 0; r < 4; ++r) {
        int oi = r0 + lkg * 4 + r;
        pv[r] = oi < M;
        pr[r] = perm[pv[r] ? oi : M - 1];
    }

    float accg[4][8];
#pragma unroll
    for (int ks = 0; ks < 4; ++ks)
#pragma unroll
        for (int j = 0; j < 8; ++j) accg[ks][j] = 0.f;

    const unsigned short* Xk = X + lkg * 8;
    for (int j = beg; j < end; j += 2) {
        int s0 = csr[j];
        const unsigned short* p0 = Xk + (size_t)s0 * HD;
        uint4 w0 = *reinterpret_cast<const uint4*>(p0);
        uint4 w1 = *reinterpret_cast<const uint4*>(p0 + 32);
        uint4 w2 = *reinterpret_cast<const uint4*>(p0 + 64);
        uint4 w3 = *reinterpret_cast<const uint4*>(p0 + 96);
        bool ok1 = (j + 1) < end;
        int s1 = csr[ok1 ? j + 1 : j];
        const unsigned short* p1 = Xk + (size_t)s1 * HD;
        uint4 y0, y1, y2, y3;
        if (ok1) {
            y0 = *reinterpret_cast<const uint4*>(p1);
            y1 = *reinterpret_cast<const uint4*>(p1 + 32);
            y2 = *reinterpret_cast<const uint4*>(p1 + 64);
            y3 = *reinterpret_cast<const uint4*>(p1 + 96);
        }
        accg[0][0] += b2f(w0.x & 0xffffu); accg[0][1] += b2f(w0.x >> 16);
        accg[0][2] += b2f(w0.y & 0xffffu); accg[0][3] += b2f(w0.y >> 16);
        accg[0][4] += b2f(w0.z & 0xffffu); accg[0][5] += b2f(w0.z >> 16);
        accg[0][6] += b2f(w0.w & 0xffffu); accg[0][7] += b2f(w0.w >> 16);
        accg[1][0] += b2f(w1.x & 0xffffu); accg[1][1] += b2f(w1.x >> 16);
        accg[1][2] += b2f(w1.y & 0xffffu); accg[1][3] += b2f(w1.y >> 16);
        accg[1][4] += b2f(w1.z & 0xffffu); accg[1][5] += b2f(w1.z >> 16);
        accg[1][6] += b2f(w1.w & 0xffffu); accg[1][7] += b2f(w1.w >> 16);
        accg[2][0] += b2f(w2.x & 0xffffu); accg[2][1] += b2f(w2.x >> 16);
        accg[2][2] += b2f(w2.y & 0xffffu); accg[2][3] += b2f(w2.y >> 16);
        accg[2][4] += b2f(w2.z & 0xffffu); accg[2][5] += b2f(w2.z >> 16);
        accg[2][6] += b2f(w2.w & 0xffffu); accg[2][7] += b2f(w2.w >> 16);
        accg[3][0] += b2f(w3.x & 0xffffu); accg[3][1] += b2f(w3.x >> 16);
        accg[3][2] += b2f(w3.y & 0xffffu); accg[3][3] += b2f(w3.y >> 16);
        accg[3][4] += b2f(w3.z & 0xffffu); accg[3][5] += b2f(w3.z >> 16);
        accg[3][6] += b2f(w3.w & 0xffffu); accg[3][7] += b2f(w3.w >> 16);
        if (ok1) {
            accg[0][0] += b2f(y0.x & 0xffffu); accg[0][1] += b2f(y0.x >> 16);
            accg[0][2] += b2f(y0.y & 0xffffu); accg[0][3] += b2f(y0.y >> 16);
            accg[0][4] += b2f(y0.z & 0xffffu); accg[0][5] += b2f(y0.z >> 16);
            accg[0][6] += b2f(y0.w & 0xffffu); accg[0][7] += b2f(y0.w >> 16);
            accg[1][0] += b2f(y1.x & 0xffffu); accg[1][1] += b2f(y1.x >> 16);
            accg[1][2] += b2f(y1.y & 0xffffu); accg[1][3] += b2f(y1.y >> 16);
            accg[1][4] += b2f(y1.z & 0xffffu); accg[1][5] += b2f(y1.z >> 16);
            accg[1][6] += b2f(y1.w & 0xffffu); accg[1][7] += b2f(y1.w >> 16);
            accg[2][0] += b2f(y2.x & 0xffffu); accg[2][1] += b2f(y2.x >> 16);
            accg[2][2] += b2f(y2.y & 0xffffu); accg[2][3] += b2f(y2.y >> 16);
            accg[2][4] += b2f(y2.z & 0xffffu); accg[2][5] += b2f(y2.z >> 16);
            accg[2][6] += b2f(y2.w & 0xffffu); accg[2][7] += b2f(y2.w >> 16);
            accg[3][0] += b2f(y3.x & 0xffffu); accg[3][1] += b2f(y3.x >> 16);
            accg[3][2] += b2f(y3.y & 0xffffu); accg[3][3] += b2f(y3.y >> 16);
            accg[3][4] += b2f(y3.z & 0xffffu); accg[3][5] += b2f(y3.z >> 16);
            accg[3][6] += b2f(y3.w & 0xffffu); accg[3][7] += b2f(y3.w >> 16);
        }
    }

    float inv = 1.f / fmaxf((float)(end - beg), 1.f);
    bf16x8 a1[4], a2f[4];
#pragma unroll
    for (int ks = 0; ks < 4; ++ks) {
        unsigned short u[8];
#pragma unroll
        for (int j = 0; j < 8; ++j) u[j] = f2b(accg[ks][j] * inv);
        a1[ks] = *reinterpret_cast<bf16x8*>(u);
    }
    const unsigned short* p2 = X + (size_t)row * HD + lkg * 8;
#pragma unroll
    for (int ks = 0; ks < 4; ++ks)
        a2f[ks] = *reinterpret_cast<const bf16x8*>(p2 + ks * 32);

    // -------- half 0: cols 0..63 --------
    {
        f32x4 acc[4];
#pragma unroll
        for (int t = 0; t < 4; ++t) {
            float b = bias[t * 16 + lrow];
            acc[t] = (f32x4){b, b, b, b};
        }
        __syncthreads();
#pragma unroll
        for (int ks = 0; ks < 4; ++ks) {
#pragma unroll
            for (int t = 0; t < 4; ++t) {
                int fi = (t * 4 + ks) * 64 + lane;
                bf16x8 bl = __builtin_bit_cast(bf16x8, wlds[fi]);
                bf16x8 br = __builtin_bit_cast(bf16x8, wlds[1024 + fi]);
                acc[t] = __builtin_amdgcn_mfma_f32_16x16x32_bf16(a1[ks], bl, acc[t], 0, 0, 0);
                acc[t] = __builtin_amdgcn_mfma_f32_16x16x32_bf16(a2f[ks], br, acc[t], 0, 0, 0);
            }
        }
#pragma unroll
        for (int t = 0; t < 4; ++t)
#pragma unroll
            for (int r = 0; r < 4; ++r)
                if (pv[r])
                    out[(size_t)pr[r] * HD + t * 16 + lrow] = f2b(fmaxf(acc[t][r], 0.f));
    }

    // -------- half 1: cols 64..127 --------
    __syncthreads();
    for (int i = threadIdx.x; i < 1024; i += 512) {
        wlds[i] = gl[frag_src_h(i, 1)];
        wlds[1024 + i] = gr[frag_src_h(i, 1)];
    }
    {
        f32x4 acc[4];
#pragma unroll
        for (int t = 0; t < 4; ++t) {
            float b = bias[(4 + t) * 16 + lrow];
            acc[t] = (f32x4){b, b, b, b};
        }
        __syncthreads();
#pragma unroll
        for (int ks = 0; ks < 4; ++ks) {
#pragma unroll
            for (int t = 0; t < 4; ++t) {
                int fi = (t * 4 + ks) * 64 + lane;
                bf16x8 bl = __builtin_bit_cast(bf16x8, wlds[fi]);
                bf16x8 br = __builtin_bit_cast(bf16x8, wlds[1024 + fi]);
                acc[t] = __builtin_amdgcn_mfma_f32_16x16x32_bf16(a1[ks], bl, acc[t], 0, 0, 0);
                acc[t] = __builtin_amdgcn_mfma_f32_16x16x32_bf16(a2f[ks], br, acc[t], 0, 0, 0);
            }
        }
#pragma unroll
        for (int t = 0; t < 4; ++t)
#pragma unroll
            for (int r = 0; r < 4; ++r)
                if (pv[r])
                    out[(size_t)pr[r] * HD + (4 + t) * 16 + lrow] = f2b(fmaxf(acc[t][r], 0.f));
    }
}

// ---------------- fused attention, frag-ordered LDS ----------------
__global__ __launch_bounds__(256) void mfma_attn(
    const unsigned short* __restrict__ A1, const unsigned short* __restrict__ W1t,
    const float* __restrict__ bias, const float* __restrict__ Wc2,
    const float* __restrict__ bc2, float* __restrict__ a2, int M)
{
    __shared__ uint4 wlds[2048];
    const int wid = threadIdx.x >> 6;
    const int lane = threadIdx.x & 63;
    const int lrow = lane & 15;
    const int lkg = lane >> 4;
    const int r0 = blockIdx.x * 128 + wid * 32;

    const uint4* g4 = reinterpret_cast<const uint4*>(W1t);
    for (int i = threadIdx.x; i < 2048; i += 256)
        wlds[i] = g4[frag_src(i)];

    bf16x8 a[2][4];
#pragma unroll
    for (int g = 0; g < 2; ++g) {
        int row = r0 + g * 16 + lrow;
        row = row < M ? row : M - 1;
        const unsigned short* p = A1 + (size_t)row * HD + lkg * 8;
#pragma unroll
        for (int ks = 0; ks < 4; ++ks)
            a[g][ks] = *reinterpret_cast<const bf16x8*>(p + ks * 32);
    }

    f32x4 acc[2][8];
#pragma unroll
    for (int t = 0; t < 8; ++t) {
        float b = bias[t * 16 + lrow];
        acc[0][t] = (f32x4){b, b, b, b};
        acc[1][t] = (f32x4){b, b, b, b};
    }

    __syncthreads();

#pragma unroll
    for (int ks = 0; ks < 4; ++ks) {
#pragma unroll
        for (int t = 0; t < 8; ++t) {
            bf16x8 b = __builtin_bit_cast(bf16x8, wlds[(t * 4 + ks) * 64 + lane]);
            acc[0][t] = __builtin_amdgcn_mfma_f32_16x16x32_bf16(a[0][ks], b, acc[0][t], 0, 0, 0);
            acc[1][t] = __builtin_amdgcn_mfma_f32_16x16x32_bf16(a[1][ks], b, acc[1][t], 0, 0, 0);
        }
    }

    float p0[2][4] = {{0.f, 0.f, 0.f, 0.f}, {0.f, 0.f, 0.f, 0.f}};
    float p1[2][4] = {{0.f, 0.f, 0.f, 0.f}, {0.f, 0.f, 0.f, 0.f}};
#pragma unroll
    for (int t = 0; t < 8; ++t) {
        float2 wv = reinterpret_cast<const float2*>(Wc2)[t * 16 + lrow];
#pragma unroll
        for (int g = 0; g < 2; ++g)
#pragma unroll
            for (int r = 0; r < 4; ++r) {
                float tv = tanhf(acc[g][t][r]);
                p0[g][r] = fmaf(tv, wv.x, p0[g][r]);
                p1[g][r] = fmaf(tv, wv.y, p1[g][r]);
            }
    }
#pragma unroll
    for (int off = 1; off < 16; off <<= 1) {
#pragma unroll
        for (int g = 0; g < 2; ++g)
#pragma unroll
            for (int r = 0; r < 4; ++r) {
                p0[g][r] += __shfl_xor(p0[g][r], off, 64);
                p1[g][r] += __shfl_xor(p1[g][r], off, 64);
            }
    }
    if (lrow == 0) {
        float B0 = bc2[0], B1 = bc2[1];
#pragma unroll
        for (int g = 0; g < 2; ++g)
#pragma unroll
            for (int r = 0; r < 4; ++r) {
                int row = r0 + g * 16 + lkg * 4 + r;
                if (row < M) {
                    float u0 = p0[g][r] + B0, u1 = p1[g][r] + B1;
                    float m = fmaxf(u0, u1);
                    float e0 = expf(u0 - m), e1 = expf(u1 - m);
                    float inv = 1.f / (e0 + e1);
                    reinterpret_cast<float2*>(a2)[row] = (float2){e0 * inv, e1 * inv};
                }
            }
    }
}

// ---------------- pos+colsum and adj merged ----------------
__global__ __launch_bounds__(1024) void k_posadj(const unsigned short* __restrict__ h,
                                                 const float* __restrict__ a2,
                                                 const int* __restrict__ batch,
                                                 const int* __restrict__ src,
                                                 const int* __restrict__ dst,
                                                 float* __restrict__ pos_out,
                                                 float* __restrict__ csum,
                                                 float* __restrict__ adj) {
    __shared__ float4 sh[16][64];
    __shared__ float shadj[NG * 4];
    int bid = blockIdx.x;
    if (bid < NG) {
        int g = bid;
        int lo = 0, hi = NN;
        while (lo < hi) { int m = (lo + hi) >> 1; if (batch[m] < g) lo = m + 1; else hi = m; }
        int beg = lo;
        hi = NN;
        while (lo < hi) { int m = (lo + hi) >> 1; if (batch[m] < g + 1) lo = m + 1; else hi = m; }
        int end = lo;
        int grp = threadIdx.x >> 6;
        int lane = threadIdx.x & 63;
        float4 acc = {0.f, 0.f, 0.f, 0.f};
        for (int i = beg + grp * 2; i < end; i += 32) {
            int i1 = i + 1;
            bool ok1 = i1 < end;
            float a0 = a2[i * 2];
            unsigned int v0 = *reinterpret_cast<const unsigned int*>(h + (size_t)i * HD + lane * 2);
            float a1 = ok1 ? a2[i1 * 2] : 0.f;
            unsigned int v1 = ok1 ? *reinterpret_cast<const unsigned int*>(h + (size_t)i1 * HD + lane * 2) : 0u;
            float f0 = b2f(v0 & 0xffffu), f1 = b2f(v0 >> 16);
            float g0 = b2f(v1 & 0xffffu), g1 = b2f(v1 >> 16);
            acc.x = fmaf(a0, f0, fmaf(a1, g0, acc.x));
            acc.y = fmaf(a0, f1, fmaf(a1, g1, acc.y));
            acc.z += f0 + g0;
            acc.w += f1 + g1;
        }
        sh[grp][lane] = acc;
        __syncthreads();
        if (threadIdx.x < 64) {
            float4 s = sh[0][lane];
#pragma unroll
            for (int k = 1; k < 16; ++k) {
                float4 t = sh[k][lane];
                s.x += t.x; s.y += t.y; s.z += t.z; s.w += t.w;
            }
            reinterpret_cast<float2*>(pos_out)[g * 64 + lane] = (float2){s.x, s.y};
            atomicAdd(&csum[lane * 2], s.z);
            atomicAdd(&csum[lane * 2 + 1], s.w);
        }
    } else {
        for (int i = threadIdx.x; i < NG * 4; i += 1024) shadj[i] = 0.f;
        __syncthreads();
        for (int e = (bid - NG) * 1024 + threadIdx.x; e < NE; e += 120 * 1024) {
            int s = src[e], d = dst[e];
            int bs = batch[s], bd = batch[d];
            if (bs != bd) continue;
            float a0s = a2[2 * s], a1s = a2[2 * s + 1];
            float a0d = a2[2 * d], a1d = a2[2 * d + 1];
            float* A = shadj + bs * 4;
            atomicAdd(A + 0, a0s * a0d);
            atomicAdd(A + 1, a0s * a1d);
            atomicAdd(A + 2, a1s * a0d);
            atomicAdd(A + 3, a1s * a1d);
        }
        __syncthreads();
        for (int i = threadIdx.x; i < NG * 4; i += 1024) {
            float v = shadj[i];
            if (v != 0.f) atomicAdd(&adj[i], v);
        }
    }
}

// ---------------- tail: gemb + penalty ----------------
__global__ __launch_bounds__(512) void k_tail(const float* __restrict__ csum,
                                              float* __restrict__ gemb_out,
                                              const float* __restrict__ adj,
                                              float* __restrict__ pen) {
    int bid = blockIdx.x;
    if (bid < 128) {
        int i = bid * 512 + threadIdx.x;
        gemb_out[i] = csum[i & 127] * (1.f / (float)NN);
    } else {
        __shared__ float sh[512];
        int g = threadIdx.x;
        float x0 = adj[g * 4], x1 = adj[g * 4 + 1], x2 = adj[g * 4 + 2], x3 = adj[g * 4 + 3];
        float l0 = fabsf(x0) + fabsf(x1);
        float l1 = fabsf(x2) + fabsf(x3);
        float d0 = x0 / fmaxf(l0, EPSV);
        float d1 = x3 / fmaxf(l1, EPSV);
        sh[g] = 0.5f * ((d0 - 1.f) * (d0 - 1.f) + (d1 - 1.f) * (d1 - 1.f));
        __syncthreads();
        for (int off = 256; off >= 1; off >>= 1) {
            if (g < off) sh[g] += sh[g + off];
            __syncthreads();
        }
        if (g == 0) pen[0] = sh[0] * (1.f / (float)NG);
    }
}

// ---------------- fp32 head GEMM ----------------
__global__ __launch_bounds__(256) void gemm_head(
    const float* __restrict__ A, const float* __restrict__ W,
    const float* __restrict__ bias, float* __restrict__ out, int M)
{
    const int tid = threadIdx.x;
    const int w = __builtin_amdgcn_readfirstlane(tid >> 6);
    const int lane = tid & 63;
    const int r0 = blockIdx.x * 32 + w * 8;
    if (r0 >= M) return;
    const int c0 = lane, c1 = lane + 64;
    float acc0[8], acc1[8];
    const float b0 = bias[c0], b1 = bias[c1];
#pragma unroll
    for (int r = 0; r < 8; ++r) { acc0[r] = b0; acc1[r] = b1; }
    const float* Ap = A + (size_t)r0 * HD;
    for (int k4 = 0; k4 < HD / 4; ++k4) {
        float4 a[8];
#pragma unroll
        for (int r = 0; r < 8; ++r)
            a[r] = *reinterpret_cast<const float4*>(Ap + r * HD + k4 * 4);
#pragma unroll
        for (int j = 0; j < 4; ++j) {
            const int k = k4 * 4 + j;
            const float w0 = W[k * HD + c0];
            const float w1 = W[k * HD + c1];
#pragma unroll
            for (int r = 0; r < 8; ++r) {
                const float av = (j == 0) ? a[r].x : (j == 1) ? a[r].y
                               : (j == 2) ? a[r].z : a[r].w;
                acc0[r] = fmaf(av, w0, acc0[r]);
                acc1[r] = fmaf(av, w1, acc1[r]);
            }
        }
    }
#pragma unroll
    for (int r = 0; r < 8; ++r) {
        out[(size_t)(r0 + r) * HD + c0] = fmaxf(acc0[r], 0.f);
        out[(size_t)(r0 + r) * HD + c1] = fmaxf(acc1[r], 0.f);
    }
}

// ---------------- final head: logits + log_softmax ----------------
__global__ void k_head(const float* __restrict__ z, const float* __restrict__ Wl2,
                       const float* __restrict__ bl2, float* __restrict__ out0) {
    int g = blockIdx.x * blockDim.x + threadIdx.x;
    if (g >= NG) return;
    float l[NC];
#pragma unroll
    for (int c = 0; c < NC; ++c) l[c] = bl2[c];
    for (int k = 0; k < HD; ++k) {
        float zv = z[(size_t)g * HD + k];
#pragma unroll
        for (int c = 0; c < NC; ++c) l[c] = fmaf(zv, Wl2[k * NC + c], l[c]);
    }
    float m = l[0];
#pragma unroll
    for (int c = 1; c < NC; ++c) m = fmaxf(m, l[c]);
    float sum = 0.f;
#pragma unroll
    for (int c = 0; c < NC; ++c) sum += expf(l[c] - m);
    float lse = m + logf(sum);
#pragma unroll
    for (int c = 0; c < NC; ++c) out0[g * NC + c] = l[c] - lse;
}

extern "C" void kernel_launch(void* const* d_in, const int* in_sizes, int n_in,
                              void* d_out, int out_size, void* d_ws, size_t ws_size,
                              hipStream_t stream) {
    const float* x   = (const float*)d_in[0];
    const int*   ei  = (const int*)d_in[1];
    const int*   src = ei;
    const int*   dst = ei + NE;
    const int*   batch = (const int*)d_in[2];
    const float* W1l = (const float*)d_in[4];
    const float* b1l = (const float*)d_in[5];
    const float* W1r = (const float*)d_in[6];
    const float* W2l = (const float*)d_in[7];
    const float* b2l = (const float*)d_in[8];
    const float* W2r = (const float*)d_in[9];
    const float* Wc1 = (const float*)d_in[10];
    const float* bc1 = (const float*)d_in[11];
    const float* Wc2 = (const float*)d_in[12];
    const float* bc2 = (const float*)d_in[13];
    const float* Wl1 = (const float*)d_in[14];
    const float* bl1 = (const float*)d_in[15];
    const float* Wl2 = (const float*)d_in[16];
    const float* bl2 = (const float*)d_in[17];

    char* ws = (char*)d_ws;
    const size_t BB = (size_t)NN * HD * 2;  // 25,600,000
    unsigned short* xb   = (unsigned short*)(ws);
    unsigned short* bufB = (unsigned short*)(ws + BB);
    size_t O = 2 * BB;  // 51,200,000
    // zeroed region (single k_zero): cnt | adj | csum  (408704 B)
    int*   cnt     = (int*)(ws + O);                 // 400000 B
    float* adj     = (float*)(ws + O + 400000);      // 8192 B
    float* csum    = (float*)(ws + O + 408192);      // 512 B
    // non-zeroed scratch
    int*   row_off = (int*)(ws + O + 408704);        // 400064 B
    int*   excl    = (int*)(ws + O + 808768);        // 400000 B
    int*   bsum    = (int*)(ws + O + 1208768);       // 4096 B
    int*   csr     = (int*)(ws + O + 1212864);       // 2560000 B
    float* a2      = (float*)(ws + O + 3772864);     // 800000 B
    float* zbuf    = (float*)(ws + O + 4572864);     // 262144 B
    int*   perm    = (int*)(ws + O + 4835008);       // 400000 B
    int*   P       = (int*)(ws + O + 5235008);       // 391*64*4 = 100096 B
    int*   totals  = (int*)(ws + O + 5335104);       // 256 B
    int*   boff    = (int*)(ws + O + 5335360);       // 256 B
    unsigned short* w1lt = (unsigned short*)(ws + O + 5335616);  // 5*32768 B
    unsigned short* w1rt = w1lt + 16384;
    unsigned short* w2lt = w1rt + 16384;
    unsigned short* w2rt = w2lt + 16384;
    unsigned short* wc1t = w2rt + 16384;

    float* out0 = (float*)d_out;     // 512*6
    float* pos  = out0 + NG * NC;    // 512*128
    float* gemb = pos + NG * HD;     // 512*128
    float* pen  = gemb + NG * HD;    // 1

    // fast zero of cnt+adj+csum
    k_zero<<<100, 256, 0, stream>>>((uint4*)(ws + O), 25544);
    // fused prep: count (first, overlaps) | cvt | weight transposes
    k_prep<<<7530, 256, 0, stream>>>(x, xb, W1l, W1r, W2l, W2r, Wc1, w1lt, dst, cnt);
    // contention-free counting sort -> perm (LPT order)
    k_hist2<<<NHB, 256, 0, stream>>>(cnt, P, NN);
    k_coltot<<<64, 512, 0, stream>>>(P, totals);
    k_binoff<<<1, 64, 0, stream>>>(totals, boff);
    k_scatter2<<<NHB, 256, 0, stream>>>(cnt, P, boff, perm, NN);
    // hierarchical scan: cnt -> row_off
    k_scan1<<<391, 256, 0, stream>>>(cnt, excl, bsum, NN);
    k_scan2<<<1, 512, 0, stream>>>(bsum, 391);
    k_scan3<<<391, 256, 0, stream>>>(excl, bsum, row_off, NN);
    // octant fill (consumes cnt via count-down)
    k_fill<<<960, 256, 0, stream>>>(src, dst, row_off, cnt, csr);

    const int SAGE_GRID = (NN + 127) / 128;  // 782
    k_sage<<<SAGE_GRID, 512, 0, stream>>>(xb, row_off, csr, perm, w1lt, w1rt, b1l, bufB, NN);
    k_sage<<<SAGE_GRID, 512, 0, stream>>>(bufB, row_off, csr, perm, w2lt, w2rt, b2l, xb, NN);
    mfma_attn<<<(NN + 127) / 128, 256, 0, stream>>>(xb, wc1t, bc1, Wc2, bc2, a2, NN);
    k_posadj<<<NG + 120, 1024, 0, stream>>>(xb, a2, batch, src, dst, pos, csum, adj);
    k_tail<<<129, 512, 0, stream>>>(csum, gemb, adj, pen);
    gemm_head<<<NG / 32, 256, 0, stream>>>(pos, Wl1, bl1, zbuf, NG);
    k_head<<<2, 256, 0, stream>>>(zbuf, Wl2, bl2, out0);
}

// Round 17
// 269.770 us; speedup vs baseline: 3.6615x; 1.0283x over previous
//
#include <hip/hip_runtime.h>

#define NN 100000
#define NE 640000
#define HD 128
#define NG 512
#define NC 6
#define EPSV 1e-5f
#define OCT 12500   // NN/8 per dst-octant
#define NHB 391     // histogram blocks (ceil(NN/256))

typedef __bf16 bf16_t;
typedef bf16_t bf16x8 __attribute__((ext_vector_type(8)));
typedef float f32x4 __attribute__((ext_vector_type(4)));

__device__ __forceinline__ float b2f(unsigned int u16) {
    return __builtin_bit_cast(float, u16 << 16);
}
__device__ __forceinline__ unsigned short f2b(float f) {
    unsigned int u = __builtin_bit_cast(unsigned int, f);
    unsigned int r = (u + 0x7fffu + ((u >> 16) & 1u)) >> 16;
    return (unsigned short)r;
}

__device__ __forceinline__ int frag_src_h(int i, int h) {
    int g2 = i >> 6, ln = i & 63;
    int row = (h * 4 + (g2 >> 2)) * 16 + (ln & 15);
    return row * 16 + (g2 & 3) * 4 + (ln >> 4);
}
__device__ __forceinline__ int frag_src(int i) {
    int g2 = i >> 6, ln = i & 63;
    int row = (g2 >> 2) * 16 + (ln & 15);
    return row * 16 + (g2 & 3) * 4 + (ln >> 4);
}

// ---------------- fast zero ----------------
__global__ __launch_bounds__(256) void k_zero(uint4* __restrict__ p, int n16) {
    int i = blockIdx.x * 256 + threadIdx.x;
    if (i < n16) p[i] = (uint4){0u, 0u, 0u, 0u};
}

// ---------------- graph boundary precompute: bnd[g] = first i with batch[i] >= g ----------------
__global__ __launch_bounds__(256) void k_bounds(const int* __restrict__ batch,
                                                int* __restrict__ bnd) {
    int i = blockIdx.x * 256 + threadIdx.x;
    if (i >= NN) return;
    int b = batch[i];
    int bp = (i == 0) ? -1 : batch[i - 1];
    for (int g = bp + 1; g <= b; ++g) bnd[g] = i;
    if (i == NN - 1)
        for (int g = b + 1; g <= NG; ++g) bnd[g] = NN;
}

// ---------------- fused prep: octant count FIRST | x->bf16 cvt | weight transposes ----------------
__global__ __launch_bounds__(256) void k_prep(
    const float* __restrict__ x, unsigned short* __restrict__ xb,
    const float* __restrict__ Wa, const float* __restrict__ Wb,
    const float* __restrict__ Wc, const float* __restrict__ Wd,
    const float* __restrict__ We, unsigned short* __restrict__ Wt,
    const int* __restrict__ dst, int* __restrict__ cnt)
{
    int bid = blockIdx.x;
    if (bid < 960) {
        int oct = bid & 7;
        int widx = bid >> 3;
        int lo = oct * OCT, hi = lo + OCT;
        for (int e = widx * 256 + threadIdx.x; e < NE; e += 120 * 256) {
            int d = dst[e];
            if (d >= lo && d < hi) atomicAdd(&cnt[d], 1);
        }
    } else if (bid < 7210) {
        int i = (bid - 960) * 256 + threadIdx.x;
        float4 v0 = reinterpret_cast<const float4*>(x)[i * 2];
        float4 v1 = reinterpret_cast<const float4*>(x)[i * 2 + 1];
        unsigned short u[8] = {f2b(v0.x), f2b(v0.y), f2b(v0.z), f2b(v0.w),
                               f2b(v1.x), f2b(v1.y), f2b(v1.z), f2b(v1.w)};
        reinterpret_cast<uint4*>(xb)[i] = *reinterpret_cast<uint4*>(u);
    } else {
        int i = (bid - 7210) * 256 + threadIdx.x;
        int w = i >> 14, r = i & 16383;
        int k = r >> 7, n = r & 127;
        const float* W = (w == 0) ? Wa : (w == 1) ? Wb : (w == 2) ? Wc : (w == 3) ? Wd : We;
        Wt[w * 16384 + n * HD + k] = f2b(W[k * HD + n]);
    }
}

// ---------------- contention-free counting sort (LPT permutation) ----------------
__global__ __launch_bounds__(256) void k_hist2(const int* __restrict__ cnt,
                                               int* __restrict__ P, int n) {
    __shared__ int h[64];
    if (threadIdx.x < 64) h[threadIdx.x] = 0;
    __syncthreads();
    int i = blockIdx.x * 256 + threadIdx.x;
    if (i < n) {
        int bin = cnt[i] < 63 ? cnt[i] : 63;
        atomicAdd(&h[bin], 1);
    }
    __syncthreads();
    if (threadIdx.x < 64) P[blockIdx.x * 64 + threadIdx.x] = h[threadIdx.x];
}

__global__ __launch_bounds__(512) void k_coltot(int* __restrict__ P,
                                                int* __restrict__ totals) {
    __shared__ int sh[512];
    int bin = blockIdx.x;
    int t = threadIdx.x;
    int v = (t < NHB) ? P[t * 64 + bin] : 0;
    sh[t] = v;
    __syncthreads();
    for (int off = 1; off < 512; off <<= 1) {
        int u = (t >= off) ? sh[t - off] : 0;
        __syncthreads();
        sh[t] += u;
        __syncthreads();
    }
    if (t < NHB) P[t * 64 + bin] = sh[t] - v;  // exclusive
    if (t == NHB - 1) totals[bin] = sh[t];
}

__global__ void k_binoff(const int* __restrict__ totals, int* __restrict__ boff) {
    int b = threadIdx.x;  // 64
    int s = 0;
    for (int j = b + 1; j < 64; ++j) s += totals[j];
    boff[b] = s;
}

__global__ __launch_bounds__(256) void k_scatter2(const int* __restrict__ cnt,
                                                  const int* __restrict__ P,
                                                  const int* __restrict__ boff,
                                                  int* __restrict__ perm, int n) {
    __shared__ int lcnt[64];
    if (threadIdx.x < 64) lcnt[threadIdx.x] = 0;
    __syncthreads();
    int i = blockIdx.x * 256 + threadIdx.x;
    if (i < n) {
        int bin = cnt[i] < 63 ? cnt[i] : 63;
        int rank = atomicAdd(&lcnt[bin], 1);
        perm[boff[bin] + P[blockIdx.x * 64 + bin] + rank] = i;
    }
}

// ---------------- hierarchical scan ----------------
__global__ void k_scan1(const int* __restrict__ cnt, int* __restrict__ excl,
                        int* __restrict__ bsum, int n) {
    __shared__ int sh[256];
    int i = blockIdx.x * 256 + threadIdx.x;
    int v = (i < n) ? cnt[i] : 0;
    sh[threadIdx.x] = v;
    __syncthreads();
    for (int off = 1; off < 256; off <<= 1) {
        int t = (threadIdx.x >= off) ? sh[threadIdx.x - off] : 0;
        __syncthreads();
        sh[threadIdx.x] += t;
        __syncthreads();
    }
    if (i < n) excl[i] = sh[threadIdx.x] - v;
    if (threadIdx.x == 255) bsum[blockIdx.x] = sh[255];
}

__global__ void k_scan2(int* bsum, int nb) {
    __shared__ int sh[512];
    int t = threadIdx.x;
    sh[t] = (t < nb) ? bsum[t] : 0;
    __syncthreads();
    for (int off = 1; off < 512; off <<= 1) {
        int v = (t >= off) ? sh[t - off] : 0;
        __syncthreads();
        sh[t] += v;
        __syncthreads();
    }
    if (t < nb) bsum[t] = sh[t];
}

__global__ void k_scan3(const int* __restrict__ excl, const int* __restrict__ bsum,
                        int* __restrict__ row_off, int n) {
    int i = blockIdx.x * 256 + threadIdx.x;
    if (i < n) row_off[i] = excl[i] + (blockIdx.x ? bsum[blockIdx.x - 1] : 0);
    if (i == 0) row_off[n] = NE;
}

// ---------------- octant-partitioned fill ----------------
__global__ __launch_bounds__(256) void k_fill(const int* __restrict__ src,
                                              const int* __restrict__ dst,
                                              const int* __restrict__ row_off,
                                              int* __restrict__ cnt,
                                              int* __restrict__ csr) {
    int q = blockIdx.x;
    int oct = q & 7;
    int widx = q >> 3;
    int lo = oct * OCT, hi = lo + OCT;
    for (int e = widx * 256 + threadIdx.x; e < NE; e += 120 * 256) {
        int d = dst[e];
        if (d >= lo && d < hi) {
            int p = atomicSub(&cnt[d], 1);
            csr[row_off[d] + p - 1] = src[e];
        }
    }
}

// ---------------- FUSED SAGE layer (degree-sorted rows via perm) ----------------
__global__ __launch_bounds__(512) void k_sage(
    const unsigned short* __restrict__ X,
    const int* __restrict__ row_off, const int* __restrict__ csr,
    const int* __restrict__ perm,
    const unsigned short* __restrict__ Wlt, const unsigned short* __restrict__ Wrt,
    const float* __restrict__ bias, unsigned short* __restrict__ out, int M)
{
    __shared__ uint4 wlds[2048];  // 32 KB
    const int wid = threadIdx.x >> 6;
    const int lane = threadIdx.x & 63;
    const int lrow = lane & 15;
    const int lkg = lane >> 4;
    const int r0 = blockIdx.x * 128 + wid * 16;

    const uint4* gl = reinterpret_cast<const uint4*>(Wlt);
    const uint4* gr = reinterpret_cast<const uint4*>(Wrt);
    for (int i = threadIdx.x; i < 1024; i += 512) {
        wlds[i] = gl[frag_src_h(i, 0)];
        wlds[1024 + i] = gr[frag_src_h(i, 0)];
    }

    int idx = r0 + lrow;
    idx = idx < M ? idx : M - 1;
    int row = perm[idx];
    int beg = row_off[row], end = row_off[row + 1];

    int pr[4];
    bool pv[4];
#pragma unroll
    for (int r = 0; r < 4; ++r) {
        int oi = r0 + lkg * 4 + r;
        pv[r] = oi < M;
        pr[r] = perm[pv[r] ? oi : M - 1];
    }

    float accg[4][8];
#pragma unroll
    for (int ks = 0; ks < 4; ++ks)
#pragma unroll
        for (int j = 0; j < 8; ++j) accg[ks][j] = 0.f;

    const unsigned short* Xk = X + lkg * 8;
    for (int j = beg; j < end; j += 2) {
        int s0 = csr[j];
        const unsigned short* p0 = Xk + (size_t)s0 * HD;
        uint4 w0 = *reinterpret_cast<const uint4*>(p0);
        uint4 w1 = *reinterpret_cast<const uint4*>(p0 + 32);
        uint4 w2 = *reinterpret_cast<const uint4*>(p0 + 64);
        uint4 w3 = *reinterpret_cast<const uint4*>(p0 + 96);
        bool ok1 = (j + 1) < end;
        int s1 = csr[ok1 ? j + 1 : j];
        const unsigned short* p1 = Xk + (size_t)s1 * HD;
        uint4 y0, y1, y2, y3;
        if (ok1) {
            y0 = *reinterpret_cast<const uint4*>(p1);
            y1 = *reinterpret_cast<const uint4*>(p1 + 32);
            y2 = *reinterpret_cast<const uint4*>(p1 + 64);
            y3 = *reinterpret_cast<const uint4*>(p1 + 96);
        }
        accg[0][0] += b2f(w0.x & 0xffffu); accg[0][1] += b2f(w0.x >> 16);
        accg[0][2] += b2f(w0.y & 0xffffu); accg[0][3] += b2f(w0.y >> 16);
        accg[0][4] += b2f(w0.z & 0xffffu); accg[0][5] += b2f(w0.z >> 16);
        accg[0][6] += b2f(w0.w & 0xffffu); accg[0][7] += b2f(w0.w >> 16);
        accg[1][0] += b2f(w1.x & 0xffffu); accg[1][1] += b2f(w1.x >> 16);
        accg[1][2] += b2f(w1.y & 0xffffu); accg[1][3] += b2f(w1.y >> 16);
        accg[1][4] += b2f(w1.z & 0xffffu); accg[1][5] += b2f(w1.z >> 16);
        accg[1][6] += b2f(w1.w & 0xffffu); accg[1][7] += b2f(w1.w >> 16);
        accg[2][0] += b2f(w2.x & 0xffffu); accg[2][1] += b2f(w2.x >> 16);
        accg[2][2] += b2f(w2.y & 0xffffu); accg[2][3] += b2f(w2.y >> 16);
        accg[2][4] += b2f(w2.z & 0xffffu); accg[2][5] += b2f(w2.z >> 16);
        accg[2][6] += b2f(w2.w & 0xffffu); accg[2][7] += b2f(w2.w >> 16);
        accg[3][0] += b2f(w3.x & 0xffffu); accg[3][1] += b2f(w3.x >> 16);
        accg[3][2] += b2f(w3.y & 0xffffu); accg[3][3] += b2f(w3.y >> 16);
        accg[3][4] += b2f(w3.z & 0xffffu); accg[3][5] += b2f(w3.z >> 16);
        accg[3][6] += b2f(w3.w & 0xffffu); accg[3][7] += b2f(w3.w >> 16);
        if (ok1) {
            accg[0][0] += b2f(y0.x & 0xffffu); accg[0][1] += b2f(y0.x >> 16);
            accg[0][2] += b2f(y0.y & 0xffffu); accg[0][3] += b2f(y0.y >> 16);
            accg[0][4] += b2f(y0.z & 0xffffu); accg[0][5] += b2f(y0.z >> 16);
            accg[0][6] += b2f(y0.w & 0xffffu); accg[0][7] += b2f(y0.w >> 16);
            accg[1][0] += b2f(y1.x & 0xffffu); accg[1][1] += b2f(y1.x >> 16);
            accg[1][2] += b2f(y1.y & 0xffffu); accg[1][3] += b2f(y1.y >> 16);
            accg[1][4] += b2f(y1.z & 0xffffu); accg[1][5] += b2f(y1.z >> 16);
            accg[1][6] += b2f(y1.w & 0xffffu); accg[1][7] += b2f(y1.w >> 16);
            accg[2][0] += b2f(y2.x & 0xffffu); accg[2][1] += b2f(y2.x >> 16);
            accg[2][2] += b2f(y2.y & 0xffffu); accg[2][3] += b2f(y2.y >> 16);
            accg[2][4] += b2f(y2.z & 0xffffu); accg[2][5] += b2f(y2.z >> 16);
            accg[2][6] += b2f(y2.w & 0xffffu); accg[2][7] += b2f(y2.w >> 16);
            accg[3][0] += b2f(y3.x & 0xffffu); accg[3][1] += b2f(y3.x >> 16);
            accg[3][2] += b2f(y3.y & 0xffffu); accg[3][3] += b2f(y3.y >> 16);
            accg[3][4] += b2f(y3.z & 0xffffu); accg[3][5] += b2f(y3.z >> 16);
            accg[3][6] += b2f(y3.w & 0xffffu); accg[3][7] += b2f(y3.w >> 16);
        }
    }

    float inv = 1.f / fmaxf((float)(end - beg), 1.f);
    bf16x8 a1[4], a2f[4];
#pragma unroll
    for (int ks = 0; ks < 4; ++ks) {
        unsigned short u[8];
#pragma unroll
        for (int j = 0; j < 8; ++j) u[j] = f2b(accg[ks][j] * inv);
        a1[ks] = *reinterpret_cast<bf16x8*>(u);
    }
    const unsigned short* p2 = X + (size_t)row * HD + lkg * 8;
#pragma unroll
    for (int ks = 0; ks < 4; ++ks)
        a2f[ks] = *reinterpret_cast<const bf16x8*>(p2 + ks * 32);

    // -------- half 0: cols 0..63 --------
    {
        f32x4 acc[4];
#pragma unroll
        for (int t = 0; t < 4; ++t) {
            float b = bias[t * 16 + lrow];
            acc[t] = (f32x4){b, b, b, b};
        }
        __syncthreads();
#pragma unroll
        for (int ks = 0; ks < 4; ++ks) {
#pragma unroll
            for (int t = 0; t < 4; ++t) {
                int fi = (t * 4 + ks) * 64 + lane;
                bf16x8 bl = __builtin_bit_cast(bf16x8, wlds[fi]);
                bf16x8 br = __builtin_bit_cast(bf16x8, wlds[1024 + fi]);
                acc[t] = __builtin_amdgcn_mfma_f32_16x16x32_bf16(a1[ks], bl, acc[t], 0, 0, 0);
                acc[t] = __builtin_amdgcn_mfma_f32_16x16x32_bf16(a2f[ks], br, acc[t], 0, 0, 0);
            }
        }
#pragma unroll
        for (int t = 0; t < 4; ++t)
#pragma unroll
            for (int r = 0; r < 4; ++r)
                if (pv[r])
                    out[(size_t)pr[r] * HD + t * 16 + lrow] = f2b(fmaxf(acc[t][r], 0.f));
    }

    // -------- half 1: cols 64..127 --------
    __syncthreads();
    for (int i = threadIdx.x; i < 1024; i += 512) {
        wlds[i] = gl[frag_src_h(i, 1)];
        wlds[1024 + i] = gr[frag_src_h(i, 1)];
    }
    {
        f32x4 acc[4];
#pragma unroll
        for (int t = 0; t < 4; ++t) {
            float b = bias[(4 + t) * 16 + lrow];
            acc[t] = (f32x4){b, b, b, b};
        }
        __syncthreads();
#pragma unroll
        for (int ks = 0; ks < 4; ++ks) {
#pragma unroll
            for (int t = 0; t < 4; ++t) {
                int fi = (t * 4 + ks) * 64 + lane;
                bf16x8 bl = __builtin_bit_cast(bf16x8, wlds[fi]);
                bf16x8 br = __builtin_bit_cast(bf16x8, wlds[1024 + fi]);
                acc[t] = __builtin_amdgcn_mfma_f32_16x16x32_bf16(a1[ks], bl, acc[t], 0, 0, 0);
                acc[t] = __builtin_amdgcn_mfma_f32_16x16x32_bf16(a2f[ks], br, acc[t], 0, 0, 0);
            }
        }
#pragma unroll
        for (int t = 0; t < 4; ++t)
#pragma unroll
            for (int r = 0; r < 4; ++r)
                if (pv[r])
                    out[(size_t)pr[r] * HD + (4 + t) * 16 + lrow] = f2b(fmaxf(acc[t][r], 0.f));
    }
}

// ---------------- fused attention, frag-ordered LDS ----------------
__global__ __launch_bounds__(256) void mfma_attn(
    const unsigned short* __restrict__ A1, const unsigned short* __restrict__ W1t,
    const float* __restrict__ bias, const float* __restrict__ Wc2,
    const float* __restrict__ bc2, float* __restrict__ a2, int M)
{
    __shared__ uint4 wlds[2048];
    const int wid = threadIdx.x >> 6;
    const int lane = threadIdx.x & 63;
    const int lrow = lane & 15;
    const int lkg = lane >> 4;
    const int r0 = blockIdx.x * 128 + wid * 32;

    const uint4* g4 = reinterpret_cast<const uint4*>(W1t);
    for (int i = threadIdx.x; i < 2048; i += 256)
        wlds[i] = g4[frag_src(i)];

    bf16x8 a[2][4];
#pragma unroll
    for (int g = 0; g < 2; ++g) {
        int row = r0 + g * 16 + lrow;
        row = row < M ? row : M - 1;
        const unsigned short* p = A1 + (size_t)row * HD + lkg * 8;
#pragma unroll
        for (int ks = 0; ks < 4; ++ks)
            a[g][ks] = *reinterpret_cast<const bf16x8*>(p + ks * 32);
    }

    f32x4 acc[2][8];
#pragma unroll
    for (int t = 0; t < 8; ++t) {
        float b = bias[t * 16 + lrow];
        acc[0][t] = (f32x4){b, b, b, b};
        acc[1][t] = (f32x4){b, b, b, b};
    }

    __syncthreads();

#pragma unroll
    for (int ks = 0; ks < 4; ++ks) {
#pragma unroll
        for (int t = 0; t < 8; ++t) {
            bf16x8 b = __builtin_bit_cast(bf16x8, wlds[(t * 4 + ks) * 64 + lane]);
            acc[0][t] = __builtin_amdgcn_mfma_f32_16x16x32_bf16(a[0][ks], b, acc[0][t], 0, 0, 0);
            acc[1][t] = __builtin_amdgcn_mfma_f32_16x16x32_bf16(a[1][ks], b, acc[1][t], 0, 0, 0);
        }
    }

    float p0[2][4] = {{0.f, 0.f, 0.f, 0.f}, {0.f, 0.f, 0.f, 0.f}};
    float p1[2][4] = {{0.f, 0.f, 0.f, 0.f}, {0.f, 0.f, 0.f, 0.f}};
#pragma unroll
    for (int t = 0; t < 8; ++t) {
        float2 wv = reinterpret_cast<const float2*>(Wc2)[t * 16 + lrow];
#pragma unroll
        for (int g = 0; g < 2; ++g)
#pragma unroll
            for (int r = 0; r < 4; ++r) {
                float tv = tanhf(acc[g][t][r]);
                p0[g][r] = fmaf(tv, wv.x, p0[g][r]);
                p1[g][r] = fmaf(tv, wv.y, p1[g][r]);
            }
    }
#pragma unroll
    for (int off = 1; off < 16; off <<= 1) {
#pragma unroll
        for (int g = 0; g < 2; ++g)
#pragma unroll
            for (int r = 0; r < 4; ++r) {
                p0[g][r] += __shfl_xor(p0[g][r], off, 64);
                p1[g][r] += __shfl_xor(p1[g][r], off, 64);
            }
    }
    if (lrow == 0) {
        float B0 = bc2[0], B1 = bc2[1];
#pragma unroll
        for (int g = 0; g < 2; ++g)
#pragma unroll
            for (int r = 0; r < 4; ++r) {
                int row = r0 + g * 16 + lkg * 4 + r;
                if (row < M) {
                    float u0 = p0[g][r] + B0, u1 = p1[g][r] + B1;
                    float m = fmaxf(u0, u1);
                    float e0 = expf(u0 - m), e1 = expf(u1 - m);
                    float inv = 1.f / (e0 + e1);
                    reinterpret_cast<float2*>(a2)[row] = (float2){e0 * inv, e1 * inv};
                }
            }
    }
}

// ---------------- pos+colsum (precomputed bounds, 4 rows/wave in flight) + adj merged ----------------
__global__ __launch_bounds__(1024) void k_posadj(const unsigned short* __restrict__ h,
                                                 const float* __restrict__ a2,
                                                 const int* __restrict__ bnd,
                                                 const int* __restrict__ batch,
                                                 const int* __restrict__ src,
                                                 const int* __restrict__ dst,
                                                 float* __restrict__ pos_out,
                                                 float* __restrict__ csum,
                                                 float* __restrict__ adj) {
    __shared__ float4 sh[16][64];
    __shared__ float shadj[NG * 4];
    int bid = blockIdx.x;
    if (bid < NG) {
        int g = bid;
        int beg = bnd[g], end = bnd[g + 1];
        int grp = threadIdx.x >> 6;
        int lane = threadIdx.x & 63;
        float4 acc = {0.f, 0.f, 0.f, 0.f};
        for (int i = beg + grp * 4; i < end; i += 64) {
            int i1 = i + 1, i2 = i + 2, i3 = i + 3;
            bool o1 = i1 < end, o2 = i2 < end, o3 = i3 < end;
            float a0 = a2[i * 2];
            unsigned int v0 = *reinterpret_cast<const unsigned int*>(h + (size_t)i * HD + lane * 2);
            float aa1 = o1 ? a2[i1 * 2] : 0.f;
            unsigned int v1 = o1 ? *reinterpret_cast<const unsigned int*>(h + (size_t)i1 * HD + lane * 2) : 0u;
            float aa2 = o2 ? a2[i2 * 2] : 0.f;
            unsigned int v2 = o2 ? *reinterpret_cast<const unsigned int*>(h + (size_t)i2 * HD + lane * 2) : 0u;
            float aa3 = o3 ? a2[i3 * 2] : 0.f;
            unsigned int v3 = o3 ? *reinterpret_cast<const unsigned int*>(h + (size_t)i3 * HD + lane * 2) : 0u;
            float f0 = b2f(v0 & 0xffffu), e0 = b2f(v0 >> 16);
            float f1 = b2f(v1 & 0xffffu), e1 = b2f(v1 >> 16);
            float f2 = b2f(v2 & 0xffffu), e2 = b2f(v2 >> 16);
            float f3 = b2f(v3 & 0xffffu), e3 = b2f(v3 >> 16);
            acc.x = fmaf(a0, f0, fmaf(aa1, f1, fmaf(aa2, f2, fmaf(aa3, f3, acc.x))));
            acc.y = fmaf(a0, e0, fmaf(aa1, e1, fmaf(aa2, e2, fmaf(aa3, e3, acc.y))));
            acc.z += (f0 + f1) + (f2 + f3);
            acc.w += (e0 + e1) + (e2 + e3);
        }
        sh[grp][lane] = acc;
        __syncthreads();
        if (threadIdx.x < 64) {
            float4 s = sh[0][lane];
#pragma unroll
            for (int k = 1; k < 16; ++k) {
                float4 t = sh[k][lane];
                s.x += t.x; s.y += t.y; s.z += t.z; s.w += t.w;
            }
            reinterpret_cast<float2*>(pos_out)[g * 64 + lane] = (float2){s.x, s.y};
            atomicAdd(&csum[lane * 2], s.z);
            atomicAdd(&csum[lane * 2 + 1], s.w);
        }
    } else {
        for (int i = threadIdx.x; i < NG * 4; i += 1024) shadj[i] = 0.f;
        __syncthreads();
        for (int e = (bid - NG) * 1024 + threadIdx.x; e < NE; e += 120 * 1024) {
            int s = src[e], d = dst[e];
            int bs = batch[s], bd = batch[d];
            if (bs != bd) continue;
            float a0s = a2[2 * s], a1s = a2[2 * s + 1];
            float a0d = a2[2 * d], a1d = a2[2 * d + 1];
            float* A = shadj + bs * 4;
            atomicAdd(A + 0, a0s * a0d);
            atomicAdd(A + 1, a0s * a1d);
            atomicAdd(A + 2, a1s * a0d);
            atomicAdd(A + 3, a1s * a1d);
        }
        __syncthreads();
        for (int i = threadIdx.x; i < NG * 4; i += 1024) {
            float v = shadj[i];
            if (v != 0.f) atomicAdd(&adj[i], v);
        }
    }
}

// ---------------- tail: gemb + penalty ----------------
__global__ __launch_bounds__(512) void k_tail(const float* __restrict__ csum,
                                              float* __restrict__ gemb_out,
                                              const float* __restrict__ adj,
                                              float* __restrict__ pen) {
    int bid = blockIdx.x;
    if (bid < 128) {
        int i = bid * 512 + threadIdx.x;
        gemb_out[i] = csum[i & 127] * (1.f / (float)NN);
    } else {
        __shared__ float sh[512];
        int g = threadIdx.x;
        float x0 = adj[g * 4], x1 = adj[g * 4 + 1], x2 = adj[g * 4 + 2], x3 = adj[g * 4 + 3];
        float l0 = fabsf(x0) + fabsf(x1);
        float l1 = fabsf(x2) + fabsf(x3);
        float d0 = x0 / fmaxf(l0, EPSV);
        float d1 = x3 / fmaxf(l1, EPSV);
        sh[g] = 0.5f * ((d0 - 1.f) * (d0 - 1.f) + (d1 - 1.f) * (d1 - 1.f));
        __syncthreads();
        for (int off = 256; off >= 1; off >>= 1) {
            if (g < off) sh[g] += sh[g + off];
            __syncthreads();
        }
        if (g == 0) pen[0] = sh[0] * (1.f / (float)NG);
    }
}

// ---------------- fp32 head GEMM ----------------
__global__ __launch_bounds__(256) void gemm_head(
    const float* __restrict__ A, const float* __restrict__ W,
    const float* __restrict__ bias, float* __restrict__ out, int M)
{
    const int tid = threadIdx.x;
    const int w = __builtin_amdgcn_readfirstlane(tid >> 6);
    const int lane = tid & 63;
    const int r0 = blockIdx.x * 32 + w * 8;
    if (r0 >= M) return;
    const int c0 = lane, c1 = lane + 64;
    float acc0[8], acc1[8];
    const float b0 = bias[c0], b1 = bias[c1];
#pragma unroll
    for (int r = 0; r < 8; ++r) { acc0[r] = b0; acc1[r] = b1; }
    const float* Ap = A + (size_t)r0 * HD;
    for (int k4 = 0; k4 < HD / 4; ++k4) {
        float4 a[8];
#pragma unroll
        for (int r = 0; r < 8; ++r)
            a[r] = *reinterpret_cast<const float4*>(Ap + r * HD + k4 * 4);
#pragma unroll
        for (int j = 0; j < 4; ++j) {
            const int k = k4 * 4 + j;
            const float w0 = W[k * HD + c0];
            const float w1 = W[k * HD + c1];
#pragma unroll
            for (int r = 0; r < 8; ++r) {
                const float av = (j == 0) ? a[r].x : (j == 1) ? a[r].y
                               : (j == 2) ? a[r].z : a[r].w;
                acc0[r] = fmaf(av, w0, acc0[r]);
                acc1[r] = fmaf(av, w1, acc1[r]);
            }
        }
    }
#pragma unroll
    for (int r = 0; r < 8; ++r) {
        out[(size_t)(r0 + r) * HD + c0] = fmaxf(acc0[r], 0.f);
        out[(size_t)(r0 + r) * HD + c1] = fmaxf(acc1[r], 0.f);
    }
}

// ---------------- final head: logits + log_softmax ----------------
__global__ void k_head(const float* __restrict__ z, const float* __restrict__ Wl2,
                       const float* __restrict__ bl2, float* __restrict__ out0) {
    int g = blockIdx.x * blockDim.x + threadIdx.x;
    if (g >= NG) return;
    float l[NC];
#pragma unroll
    for (int c = 0; c < NC; ++c) l[c] = bl2[c];
    for (int k = 0; k < HD; ++k) {
        float zv = z[(size_t)g * HD + k];
#pragma unroll
        for (int c = 0; c < NC; ++c) l[c] = fmaf(zv, Wl2[k * NC + c], l[c]);
    }
    float m = l[0];
#pragma unroll
    for (int c = 1; c < NC; ++c) m = fmaxf(m, l[c]);
    float sum = 0.f;
#pragma unroll
    for (int c = 0; c < NC; ++c) sum += expf(l[c] - m);
    float lse = m + logf(sum);
#pragma unroll
    for (int c = 0; c < NC; ++c) out0[g * NC + c] = l[c] - lse;
}

extern "C" void kernel_launch(void* const* d_in, const int* in_sizes, int n_in,
                              void* d_out, int out_size, void* d_ws, size_t ws_size,
                              hipStream_t stream) {
    const float* x   = (const float*)d_in[0];
    const int*   ei  = (const int*)d_in[1];
    const int*   src = ei;
    const int*   dst = ei + NE;
    const int*   batch = (const int*)d_in[2];
    const float* W1l = (const float*)d_in[4];
    const float* b1l = (const float*)d_in[5];
    const float* W1r = (const float*)d_in[6];
    const float* W2l = (const float*)d_in[7];
    const float* b2l = (const float*)d_in[8];
    const float* W2r = (const float*)d_in[9];
    const float* Wc1 = (const float*)d_in[10];
    const float* bc1 = (const float*)d_in[11];
    const float* Wc2 = (const float*)d_in[12];
    const float* bc2 = (const float*)d_in[13];
    const float* Wl1 = (const float*)d_in[14];
    const float* bl1 = (const float*)d_in[15];
    const float* Wl2 = (const float*)d_in[16];
    const float* bl2 = (const float*)d_in[17];

    char* ws = (char*)d_ws;
    const size_t BB = (size_t)NN * HD * 2;  // 25,600,000
    unsigned short* xb   = (unsigned short*)(ws);
    unsigned short* bufB = (unsigned short*)(ws + BB);
    size_t O = 2 * BB;  // 51,200,000
    // zeroed region (single k_zero): cnt | adj | csum  (408704 B)
    int*   cnt     = (int*)(ws + O);                 // 400000 B
    float* adj     = (float*)(ws + O + 400000);      // 8192 B
    float* csum    = (float*)(ws + O + 408192);      // 512 B
    // non-zeroed scratch
    int*   row_off = (int*)(ws + O + 408704);        // 400064 B
    int*   excl    = (int*)(ws + O + 808768);        // 400000 B
    int*   bsum    = (int*)(ws + O + 1208768);       // 4096 B
    int*   csr     = (int*)(ws + O + 1212864);       // 2560000 B
    float* a2      = (float*)(ws + O + 3772864);     // 800000 B
    float* zbuf    = (float*)(ws + O + 4572864);     // 262144 B
    int*   perm    = (int*)(ws + O + 4835008);       // 400000 B
    int*   P       = (int*)(ws + O + 5235008);       // 100096 B
    int*   totals  = (int*)(ws + O + 5335104);       // 256 B
    int*   boff    = (int*)(ws + O + 5335360);       // 256 B
    int*   bnd     = (int*)(ws + O + 5335616);       // 2052 B (NG+1 ints)
    unsigned short* w1lt = (unsigned short*)(ws + O + 5337668 + 60);  // align to 4 anyway
    w1lt = (unsigned short*)(ws + O + 5337728);      // 5*32768 B
    unsigned short* w1rt = w1lt + 16384;
    unsigned short* w2lt = w1rt + 16384;
    unsigned short* w2rt = w2lt + 16384;
    unsigned short* wc1t = w2rt + 16384;

    float* out0 = (float*)d_out;     // 512*6
    float* pos  = out0 + NG * NC;    // 512*128
    float* gemb = pos + NG * HD;     // 512*128
    float* pen  = gemb + NG * HD;    // 1

    // fast zero of cnt+adj+csum
    k_zero<<<100, 256, 0, stream>>>((uint4*)(ws + O), 25544);
    // graph bounds (independent; overlaps with prep)
    k_bounds<<<NHB, 256, 0, stream>>>(batch, bnd);
    // fused prep: count (first, overlaps) | cvt | weight transposes
    k_prep<<<7530, 256, 0, stream>>>(x, xb, W1l, W1r, W2l, W2r, Wc1, w1lt, dst, cnt);
    // contention-free counting sort -> perm (LPT order)
    k_hist2<<<NHB, 256, 0, stream>>>(cnt, P, NN);
    k_coltot<<<64, 512, 0, stream>>>(P, totals);
    k_binoff<<<1, 64, 0, stream>>>(totals, boff);
    k_scatter2<<<NHB, 256, 0, stream>>>(cnt, P, boff, perm, NN);
    // hierarchical scan: cnt -> row_off
    k_scan1<<<391, 256, 0, stream>>>(cnt, excl, bsum, NN);
    k_scan2<<<1, 512, 0, stream>>>(bsum, 391);
    k_scan3<<<391, 256, 0, stream>>>(excl, bsum, row_off, NN);
    // octant fill (consumes cnt via count-down)
    k_fill<<<960, 256, 0, stream>>>(src, dst, row_off, cnt, csr);

    const int SAGE_GRID = (NN + 127) / 128;  // 782
    k_sage<<<SAGE_GRID, 512, 0, stream>>>(xb, row_off, csr, perm, w1lt, w1rt, b1l, bufB, NN);
    k_sage<<<SAGE_GRID, 512, 0, stream>>>(bufB, row_off, csr, perm, w2lt, w2rt, b2l, xb, NN);
    mfma_attn<<<(NN + 127) / 128, 256, 0, stream>>>(xb, wc1t, bc1, Wc2, bc2, a2, NN);
    k_posadj<<<NG + 120, 1024, 0, stream>>>(xb, a2, bnd, batch, src, dst, pos, csum, adj);
    k_tail<<<129, 512, 0, stream>>>(csum, gemb, adj, pen);
    gemm_head<<<NG / 32, 256, 0, stream>>>(pos, Wl1, bl1, zbuf, NG);
    k_head<<<2, 256, 0, stream>>>(zbuf, Wl2, bl2, out0);
}